// Round 6
// baseline (4004.496 us; speedup 1.0000x reference)
//
#include <hip/hip_runtime.h>
#include <hip/hip_bf16.h>

#define N_NODES 10000
#define N_EDGES 160000
#define N_GRAPHS 64
#define NK 5
#define EPS 1e-5f
#define EPW 32           // edges per wave (autonomous)
#define EPB 128          // edges per block = 4 waves x 32
#define JP 648           // packed width for Pab halves
#define PSTRIDE 1296     // Pab row stride: [Pa 648 | Pb 648]
#define TCOLS 648        // table row width (642 -> 648)
#define TROWS 12289      // d2 grid [0,96], h=1/128
#define IMAX 12287
#define ZSTR 34          // Zw row stride (words): even -> b64-aligned pair reads
#define WSTR 36          // W2w row stride (words): 144B -> b128-aligned

__device__ __forceinline__ float silu(float x) { return x / (1.0f + __expf(-x)); }
__device__ __forceinline__ float4 f4fma(float s, float4 w, float4 a) {
    a.x = fmaf(s, w.x, a.x); a.y = fmaf(s, w.y, a.y);
    a.z = fmaf(s, w.z, a.z); a.w = fmaf(s, w.w, a.w);
    return a;
}
__device__ __forceinline__ float wave_sum64(float v) {
    #pragma unroll
    for (int off = 32; off > 0; off >>= 1) v += __shfl_xor(v, off, 64);
    return v;
}

// ---------------- embedding ----------------
__global__ __launch_bounds__(128) void k_embed(const int* __restrict__ atomids,
                                               const float* __restrict__ emb_w,
                                               float* __restrict__ feats_all) {
    int n = blockIdx.x, tid = threadIdx.x;
    feats_all[(size_t)n * 768 + tid] = emb_w[(size_t)atomids[n] * 128 + tid];
}

// ---------------- per-edge squared distance ----------------
__global__ __launch_bounds__(256) void k_d2(const float* __restrict__ coords,
                                            const int* __restrict__ eidx,
                                            float* __restrict__ d2g) {
    int e = blockIdx.x * 256 + threadIdx.x;
    if (e >= N_EDGES) return;
    int s = eidx[e], d = eidx[N_EDGES + e];
    float dx = coords[s * 3 + 0] - coords[d * 3 + 0];
    float dy = coords[s * 3 + 1] - coords[d * 3 + 1];
    float dz = coords[s * 3 + 2] - coords[d * 3 + 2];
    d2g[e] = dx * dx + dy * dy + dz * dz;
}

// ---------------- in-degree (layer-invariant) ----------------
__global__ __launch_bounds__(256) void k_cnt(const int* __restrict__ eidx,
                                             float* __restrict__ cnt) {
    int e = blockIdx.x * 256 + threadIdx.x;
    if (e >= N_EDGES) return;
    atomicAdd(&cnt[eidx[N_EDGES + e]], 1.0f);
}

// ---------------- counting sort of edges by i0 (T-row index) ----------------
__global__ __launch_bounds__(256) void k_hist(const float* __restrict__ d2g,
                                              int* __restrict__ hist) {
    int e = blockIdx.x * 256 + threadIdx.x;
    if (e >= N_EDGES) return;
    int i0 = (int)(d2g[e] * 128.0f);
    if (i0 > IMAX) i0 = IMAX;
    atomicAdd(&hist[i0], 1);
}

__global__ __launch_bounds__(256) void k_scan(const int* __restrict__ hist,
                                              int* __restrict__ offs) {
    __shared__ int buf[256];
    __shared__ int carryS;
    int tid = threadIdx.x;
    if (tid == 0) carryS = 0;
    __syncthreads();
    for (int base = 0; base < TROWS; base += 256) {
        int v = (base + tid < TROWS) ? hist[base + tid] : 0;
        buf[tid] = v;
        __syncthreads();
        for (int off = 1; off < 256; off <<= 1) {
            int t = (tid >= off) ? buf[tid - off] : 0;
            __syncthreads();
            buf[tid] += t;
            __syncthreads();
        }
        if (base + tid < TROWS) offs[base + tid] = carryS + buf[tid] - v;  // exclusive
        __syncthreads();
        if (tid == 0) carryS += buf[255];
        __syncthreads();
    }
}

__global__ __launch_bounds__(256) void k_copyi(const int* __restrict__ a,
                                               int* __restrict__ b) {
    int i = blockIdx.x * 256 + threadIdx.x;
    if (i < TROWS) b[i] = a[i];
}

__global__ __launch_bounds__(256) void k_scatter(const int* __restrict__ eidx,
                                                 const float* __restrict__ d2g,
                                                 int* __restrict__ cursor,
                                                 int* __restrict__ ssiP,
                                                 int* __restrict__ dsiP,
                                                 int* __restrict__ i0P,
                                                 float* __restrict__ frP) {
    int e = blockIdx.x * 256 + threadIdx.x;
    if (e >= N_EDGES) return;
    float t = d2g[e] * 128.0f;
    int i0 = (int)t;
    if (i0 > IMAX) i0 = IMAX;
    float fr = t - (float)i0;
    int pos = atomicAdd(&cursor[i0], 1);
    ssiP[pos] = eidx[e];
    dsiP[pos] = eidx[N_EDGES + e];
    i0P[pos] = i0;
    frP[pos] = fr;
}

// ---------------- fourier features on the d2 GRID (once) ----------------
__global__ __launch_bounds__(256) void k_feg(float* __restrict__ feG) {  // [TROWS][68]
    int g = blockIdx.x * 256 + threadIdx.x;
    if (g >= TROWS) return;
    float d2v = (float)g * 0.0078125f;   // g / 128, exact
    float* o = feG + (size_t)g * 68;
    float sc = 1.0f;
    #pragma unroll
    for (int i = 0; i < 32; ++i) {
        float x = d2v * sc;
        o[i] = sinf(x);
        o[32 + i] = cosf(x);
        sc *= 0.5f;
    }
    o[64] = d2v;
}

// ---------------- per-layer q-table: T[g][j] = fe(g/128) @ W1c + b1 ----------------
__global__ __launch_bounds__(256) void k_tab(const float* __restrict__ feG,   // [TROWS][68]
                                             const float* __restrict__ W1cp,  // [65][768]
                                             const float* __restrict__ b1p,   // [768]
                                             float* __restrict__ T) {         // [TROWS][648]
    __shared__ float feGs[32 * 68];
    __shared__ float W1s[65 * 36];
    const int tid = threadIdx.x;
    const int g0 = blockIdx.x * 32;
    for (int idx = tid; idx < 32 * 17; idx += 256) {
        int r = idx / 17, c = idx - r * 17;
        int gi = g0 + r;
        float4 v = make_float4(0, 0, 0, 0);
        if (gi < TROWS) v = *(const float4*)(feG + (size_t)gi * 68 + 4 * c);
        *(float4*)&feGs[r * 68 + 4 * c] = v;
    }
    const int gt = tid >> 3, ct = tid & 7;
    for (int jc = 0; jc < TCOLS; jc += 32) {
        __syncthreads();
        for (int idx = tid; idx < 65 * 32; idx += 256) {
            int k = idx >> 5, j = idx & 31;
            W1s[k * 36 + j] = W1cp[(size_t)k * 768 + jc + j];
        }
        __syncthreads();
        int gj = jc + 4 * ct;
        float4 q = *(const float4*)(b1p + gj);
        #pragma unroll 5
        for (int k = 0; k < 65; ++k) {
            float f = feGs[gt * 68 + k];
            float4 w = *(const float4*)&W1s[k * 36 + 4 * ct];
            q = f4fma(f, w, q);
        }
        int g = g0 + gt;
        if (g < TROWS && gj < TCOLS)
            *(float4*)(T + (size_t)g * TCOLS + gj) = q;
    }
}

// ---------------- W1ab prestage, all 5 layers: [5][128][1296] = [W1a|0|W1b|0] packed ----------------
__global__ __launch_bounds__(256) void k_w1ab5(const float* __restrict__ eW1,
                                               float* __restrict__ W1ab5) {
    int k = blockIdx.y;
    const float* W1 = eW1 + (size_t)k * 321 * 642;
    float* W1ab = W1ab5 + (size_t)k * 128 * 1296;
    int idx = blockIdx.x * 256 + threadIdx.x;
    if (idx >= 128 * 1296) return;
    int r = idx / 1296;
    int j = idx - r * 1296;
    float v = 0.f;
    if (j < 642) v = W1[(size_t)r * 642 + j];
    else if (j >= 648 && j < 1290) v = W1[(size_t)(128 + r) * 642 + (j - 648)];
    W1ab[idx] = v;
}

// ---------------- padded edge-weight prestage (all 5 layers) ----------------
__global__ __launch_bounds__(256) void k_wpre5(const float* __restrict__ eW1,
                                               const float* __restrict__ eb1,
                                               const float* __restrict__ eW2,
                                               float* __restrict__ W1cp5,   // [5][65][768]
                                               float* __restrict__ b1p5,    // [5][768]
                                               float* __restrict__ W2p5) {  // [5][768][32]
    int k = blockIdx.y;
    const float* W1 = eW1 + (size_t)k * 321 * 642;
    const float* b1 = eb1 + (size_t)k * 642;
    const float* W2 = eW2 + (size_t)k * 642 * 32;
    float* W1cp = W1cp5 + (size_t)k * 65 * 768;
    float* b1p  = b1p5 + (size_t)k * 768;
    float* W2p  = W2p5 + (size_t)k * 768 * 32;
    int idx = blockIdx.x * 256 + threadIdx.x;
    if (idx < 65 * 768) {
        int r = idx / 768, j = idx - r * 768;
        W1cp[idx] = (j < 642) ? W1[(size_t)(256 + r) * 642 + j] : 0.f;
    } else if (idx < 65 * 768 + 768) {
        int j = idx - 65 * 768;
        b1p[j] = (j < 642) ? b1[j] : 0.f;
    } else if (idx < 65 * 768 + 768 + 768 * 32) {
        int t = idx - (65 * 768 + 768);
        int j = t >> 5, c = t & 31;
        W2p[t] = (j < 642) ? W2[(size_t)j * 32 + c] : 0.f;
    }
}

// ---------------- fp32 GEMM: C = act(actA(A)[M][K] @ B[K][N] + bias) ----------------
__global__ __launch_bounds__(256) void k_gemm(const float* __restrict__ A, int lda,
                                              const float* __restrict__ B, int ldb,
                                              const float* __restrict__ bias,
                                              float* __restrict__ C, int ldc,
                                              int M, int N, int K, int siluA, int siluOut) {
    __shared__ float As[32 * 132];
    __shared__ float Bs[32 * 132];
    const int tid = threadIdx.x;
    const int m0 = blockIdx.x * 128, n0 = blockIdx.y * 128;
    const int tm = tid >> 4, tn = tid & 15;

    float4 acc[8][2];
    #pragma unroll
    for (int r = 0; r < 8; ++r) { acc[r][0] = make_float4(0,0,0,0); acc[r][1] = make_float4(0,0,0,0); }

    float4 ra[4], rb[4];

#define GLOAD(kc_) do { \
    _Pragma("unroll") \
    for (int i_ = 0; i_ < 4; ++i_) { \
        int idx_ = tid + i_ * 256; \
        int m_ = idx_ >> 3, kq_ = idx_ & 7; \
        int gm_ = m0 + m_; \
        int cm_ = (gm_ < M) ? gm_ : (M - 1); \
        float4 a_ = *(const float4*)(A + (size_t)cm_ * lda + (kc_) + 4 * kq_); \
        if (gm_ >= M) a_ = make_float4(0,0,0,0); \
        ra[i_] = a_; \
    } \
    _Pragma("unroll") \
    for (int i_ = 0; i_ < 4; ++i_) { \
        int idx_ = tid + i_ * 256; \
        int r_ = idx_ >> 5, cq_ = idx_ & 31; \
        int gn_ = n0 + 4 * cq_; \
        float4 b_ = make_float4(0,0,0,0); \
        if (gn_ < N) b_ = *(const float4*)(B + (size_t)((kc_) + r_) * ldb + gn_); \
        rb[i_] = b_; \
    } \
} while (0)

    GLOAD(0);

    for (int kc = 0; kc < K; kc += 32) {
        #pragma unroll
        for (int i = 0; i < 4; ++i) {
            int idx = tid + i * 256;
            int m = idx >> 3, kq = idx & 7;
            float4 a = ra[i];
            if (siluA) { a.x = silu(a.x); a.y = silu(a.y); a.z = silu(a.z); a.w = silu(a.w); }
            As[(4 * kq + 0) * 132 + m] = a.x;
            As[(4 * kq + 1) * 132 + m] = a.y;
            As[(4 * kq + 2) * 132 + m] = a.z;
            As[(4 * kq + 3) * 132 + m] = a.w;
        }
        #pragma unroll
        for (int i = 0; i < 4; ++i) {
            int idx = tid + i * 256;
            int r = idx >> 5, cq = idx & 31;
            *(float4*)&Bs[r * 132 + 4 * cq] = rb[i];
        }
        __syncthreads();
        if (kc + 32 < K) GLOAD(kc + 32);   // in flight during FMA below
        #pragma unroll 4
        for (int kk = 0; kk < 32; ++kk) {
            float4 a0 = *(const float4*)&As[kk * 132 + 8 * tm];
            float4 a1 = *(const float4*)&As[kk * 132 + 8 * tm + 4];
            float4 b0 = *(const float4*)&Bs[kk * 132 + 4 * tn];
            float4 b1 = *(const float4*)&Bs[kk * 132 + 64 + 4 * tn];
            acc[0][0] = f4fma(a0.x, b0, acc[0][0]); acc[0][1] = f4fma(a0.x, b1, acc[0][1]);
            acc[1][0] = f4fma(a0.y, b0, acc[1][0]); acc[1][1] = f4fma(a0.y, b1, acc[1][1]);
            acc[2][0] = f4fma(a0.z, b0, acc[2][0]); acc[2][1] = f4fma(a0.z, b1, acc[2][1]);
            acc[3][0] = f4fma(a0.w, b0, acc[3][0]); acc[3][1] = f4fma(a0.w, b1, acc[3][1]);
            acc[4][0] = f4fma(a1.x, b0, acc[4][0]); acc[4][1] = f4fma(a1.x, b1, acc[4][1]);
            acc[5][0] = f4fma(a1.y, b0, acc[5][0]); acc[5][1] = f4fma(a1.y, b1, acc[5][1]);
            acc[6][0] = f4fma(a1.z, b0, acc[6][0]); acc[6][1] = f4fma(a1.z, b1, acc[6][1]);
            acc[7][0] = f4fma(a1.w, b0, acc[7][0]); acc[7][1] = f4fma(a1.w, b1, acc[7][1]);
        }
        __syncthreads();
    }
#undef GLOAD

    const int gnl = n0 + 4 * tn, gnh = n0 + 64 + 4 * tn;
    #pragma unroll
    for (int r = 0; r < 8; ++r) {
        int gm = m0 + 8 * tm + r;
        if (gm >= M) continue;
        float4 v0 = acc[r][0], v1 = acc[r][1];
        if (gnl < N) {
            if (bias) { v0.x += bias[gnl+0]; v0.y += bias[gnl+1]; v0.z += bias[gnl+2]; v0.w += bias[gnl+3]; }
            if (siluOut) { v0.x = silu(v0.x); v0.y = silu(v0.y); v0.z = silu(v0.z); v0.w = silu(v0.w); }
            *(float4*)&C[(size_t)gm * ldc + gnl] = v0;
        }
        if (gnh < N) {
            if (bias) { v1.x += bias[gnh+0]; v1.y += bias[gnh+1]; v1.z += bias[gnh+2]; v1.w += bias[gnh+3]; }
            if (siluOut) { v1.x = silu(v1.x); v1.y = silu(v1.y); v1.z = silu(v1.z); v1.w = silu(v1.w); }
            *(float4*)&C[(size_t)gm * ldc + gnh] = v1;
        }
    }
}

// ---------------- fused edge kernel v5: wave-autonomous, ZERO barriers ----------------
// v2-v4 post-mortem: VALUBusy pinned 40-46% because all 4 waves are barrier-convoyed
// (2 __syncthreads/chunk for Zs/W2s sharing); register prefetch defeated (VGPR 84).
// v5: each WAVE owns 32 edges end-to-end with per-wave Zw/W2w LDS slices -> no
// __syncthreads at all. Wave-internal LDS ordering via s_waitcnt lgkmcnt(0) (per-wave
// LDS pipe is in-order). Manual pipeline: issue chunk ch+1's 40 float4 global loads
// BEFORE FMA(ch) (~2000cy) -> latency covered; launch_bounds(256,2) gives 256-VGPR cap
// so the ~160 in-flight load regs can stay live. 8 independent waves/CU hide the rest.
// Phase-1: lane=(edge u=ln&31, col-half ln>>5); phase-2: lane=(pair p=ln>>2, ocq=ln&3),
// edges (p, p+16) stored adjacent in Zw for b64 reads. j ascends chunk-major, kk-minor
// exactly as v2-v4 -> accumulators bit-identical. Chunk 10 cols >=648: addresses clamped
// (finite garbage) and annihilated by zero-padded W2p rows (j>=642 are 0) -> exact zeros.
// LDS layouts: Zw stride 34 (b64-aligned pair reads, conflict-free), W2w stride 36
// (b128-aligned; reads conflict-free, writes ~8-way but only 8/chunk).
__global__ __launch_bounds__(256, 2) void k_edge(const int* __restrict__ ssiP,
                                                 const int* __restrict__ dsiP,
                                                 const int* __restrict__ i0P,
                                                 const float* __restrict__ frP,
                                                 const float* __restrict__ T,     // [TROWS][648]
                                                 const float* __restrict__ Pab,   // [N_NODES][1296]
                                                 const float* __restrict__ W2p,   // [768][32]
                                                 const float* __restrict__ b2,
                                                 const float* __restrict__ eng,
                                                 const float* __restrict__ enb,
                                                 float* __restrict__ S) {
    __shared__ float Zw[4][64 * ZSTR];    // per-wave z: [j 0..63][paircol 0..31], 8.5KB/wave
    __shared__ float W2w[4][64 * WSTR];   // per-wave W2 chunk: [row][oc], 9KB/wave

    const int tid = threadIdx.x;
    const int wid = tid >> 6;
    const int ln  = tid & 63;

    // XCD-chunked bijective swizzle: nwg=1250, 8 XCDs -> q=156, r=2 (xcd 0,1 get 157)
    const int bid = blockIdx.x;
    const int xcd = bid & 7, bpos = bid >> 3;
    const int wg = (xcd < 2) ? xcd * 157 + bpos : 314 + (xcd - 2) * 156 + bpos;
    const int ebase = wg * EPB + wid * EPW;

    float* Zp = Zw[wid];
    float* Wp = W2w[wid];

    // ---- phase-1 identity: edge u, column half chh (32 cols each) ----
    const int u   = ln & 31;
    const int chh = ln >> 5;
    const int cu  = 2 * (u & 15) + (u >> 4);   // Zw column: pairs (e, e+16) adjacent

    const int eg   = ebase + u;
    const int i0r  = i0P[eg];
    const float frr = frP[eg];
    const int srcr = ssiP[eg];
    const int dstr = dsiP[eg];

    const float* Trow  = T + (size_t)i0r * TCOLS;
    const float* PaRow = Pab + (size_t)dstr * PSTRIDE;
    const float* PbRow = Pab + (size_t)srcr * PSTRIDE + JP;

    // ---- phase-2 identity: pair p (edges p, p+16), oc-quad ocq (8 contiguous oc) ----
    const int p   = ln >> 2;
    const int ocq = ln & 3;

    float4 acc10 = make_float4(0,0,0,0), acc11 = make_float4(0,0,0,0);
    float4 acc20 = make_float4(0,0,0,0), acc21 = make_float4(0,0,0,0);

    // in-flight load registers (held across the FMA phase)
    float4 rTa[8], rTb[8], rPa[8], rPb[8], rW[8];

#define LOADCH(CH) do { \
    const int c0_ = 64 * (CH) + 32 * chh; \
    _Pragma("unroll") \
    for (int q_ = 0; q_ < 8; ++q_) { \
        int c_ = c0_ + 4 * q_; if (c_ > 644) c_ = 644;  /* clamp: finite, killed by W2=0 */ \
        rTa[q_] = *(const float4*)(Trow + c_); \
        rTb[q_] = *(const float4*)(Trow + TCOLS + c_); \
        rPa[q_] = *(const float4*)(PaRow + c_); \
        rPb[q_] = *(const float4*)(PbRow + c_); \
    } \
    { const float* ws_ = W2p + (size_t)(64 * (CH) + ln) * 32; \
      _Pragma("unroll") \
      for (int q_ = 0; q_ < 8; ++q_) rW[q_] = *(const float4*)(ws_ + 4 * q_); } \
} while (0)

#define ZSTORE() do { \
    _Pragma("unroll") \
    for (int q_ = 0; q_ < 8; ++q_) { \
        float4 a_ = rTa[q_], b_ = rTb[q_], pa_ = rPa[q_], pb_ = rPb[q_]; \
        const int jb_ = 32 * chh + 4 * q_; \
        Zp[(jb_ + 0) * ZSTR + cu] = silu(fmaf(frr, b_.x - a_.x, a_.x) + pa_.x + pb_.x); \
        Zp[(jb_ + 1) * ZSTR + cu] = silu(fmaf(frr, b_.y - a_.y, a_.y) + pa_.y + pb_.y); \
        Zp[(jb_ + 2) * ZSTR + cu] = silu(fmaf(frr, b_.z - a_.z, a_.z) + pa_.z + pb_.z); \
        Zp[(jb_ + 3) * ZSTR + cu] = silu(fmaf(frr, b_.w - a_.w, a_.w) + pa_.w + pb_.w); \
    } \
    _Pragma("unroll") \
    for (int q_ = 0; q_ < 8; ++q_) *(float4*)(Wp + ln * WSTR + 4 * q_) = rW[q_]; \
} while (0)

    // prologue: load + z-compute + store chunk 0
    LOADCH(0);
    ZSTORE();

    for (int ch = 0; ch < 11; ++ch) {
        if (ch < 10) LOADCH(ch + 1);   // issued BEFORE FMA -> flies under it
        asm volatile("s_waitcnt lgkmcnt(0)" ::: "memory");   // Zw/W2w(ch) visible (per-wave)
        #pragma unroll 8
        for (int kk = 0; kk < 64; ++kk) {
            float2 z2 = *(const float2*)(Zp + kk * ZSTR + 2 * p);
            float4 wA = *(const float4*)(Wp + kk * WSTR + 8 * ocq);
            float4 wB = *(const float4*)(Wp + kk * WSTR + 8 * ocq + 4);
            acc10 = f4fma(z2.x, wA, acc10); acc11 = f4fma(z2.x, wB, acc11);
            acc20 = f4fma(z2.y, wA, acc20); acc21 = f4fma(z2.y, wB, acc21);
        }
        if (ch < 10) ZSTORE();   // WAR on Zw/Wp safe: per-wave LDS ops are in-order
    }
#undef LOADCH
#undef ZSTORE

    // ---- epilogue (barrier-free): m2 = silu(acc + b2), LN over 32 oc, scatter ----
    {
        float4 bb0 = *(const float4*)(b2 + 8 * ocq);
        float4 bb1 = *(const float4*)(b2 + 8 * ocq + 4);
        float m1[8], m2e[8];
        m1[0] = silu(acc10.x + bb0.x); m1[1] = silu(acc10.y + bb0.y);
        m1[2] = silu(acc10.z + bb0.z); m1[3] = silu(acc10.w + bb0.w);
        m1[4] = silu(acc11.x + bb1.x); m1[5] = silu(acc11.y + bb1.y);
        m1[6] = silu(acc11.z + bb1.z); m1[7] = silu(acc11.w + bb1.w);
        m2e[0] = silu(acc20.x + bb0.x); m2e[1] = silu(acc20.y + bb0.y);
        m2e[2] = silu(acc20.z + bb0.z); m2e[3] = silu(acc20.w + bb0.w);
        m2e[4] = silu(acc21.x + bb1.x); m2e[5] = silu(acc21.y + bb1.y);
        m2e[6] = silu(acc21.z + bb1.z); m2e[7] = silu(acc21.w + bb1.w);

        float s1 = 0.f, ss1 = 0.f, s2 = 0.f, ss2 = 0.f;
        #pragma unroll
        for (int c = 0; c < 8; ++c) {
            s1 += m1[c];  ss1 += m1[c] * m1[c];
            s2 += m2e[c]; ss2 += m2e[c] * m2e[c];
        }
        s1  += __shfl_xor(s1, 1, 64);  ss1 += __shfl_xor(ss1, 1, 64);
        s1  += __shfl_xor(s1, 2, 64);  ss1 += __shfl_xor(ss1, 2, 64);
        s2  += __shfl_xor(s2, 1, 64);  ss2 += __shfl_xor(ss2, 1, 64);
        s2  += __shfl_xor(s2, 2, 64);  ss2 += __shfl_xor(ss2, 2, 64);

        float mean1 = s1 * 0.03125f;
        float var1  = ss1 * 0.03125f - mean1 * mean1;
        float rstd1 = 1.0f / sqrtf(var1 + EPS);
        float mean2 = s2 * 0.03125f;
        float var2  = ss2 * 0.03125f - mean2 * mean2;
        float rstd2 = 1.0f / sqrtf(var2 + EPS);

        const int dst1 = dsiP[ebase + p];
        const int dst2 = dsiP[ebase + p + 16];
        float4 g0 = *(const float4*)(eng + 8 * ocq);
        float4 g1 = *(const float4*)(eng + 8 * ocq + 4);
        float4 e0 = *(const float4*)(enb + 8 * ocq);
        float4 e1 = *(const float4*)(enb + 8 * ocq + 4);
        float gg[8] = {g0.x, g0.y, g0.z, g0.w, g1.x, g1.y, g1.z, g1.w};
        float ee[8] = {e0.x, e0.y, e0.z, e0.w, e1.x, e1.y, e1.z, e1.w};

        float* Sp1 = S + (size_t)dst1 * 32 + 8 * ocq;
        float* Sp2 = S + (size_t)dst2 * 32 + 8 * ocq;
        #pragma unroll
        for (int c = 0; c < 8; ++c) {
            atomicAdd(&Sp1[c], (m1[c]  - mean1) * rstd1 * gg[c] + ee[c]);
            atomicAdd(&Sp2[c], (m2e[c] - mean2) * rstd2 * gg[c] + ee[c]);
        }
    }
}

// ---------------- node prep: H0 = [LN(feats) | LN(S/cnt)] ----------------
__global__ __launch_bounds__(128) void k_prep(const float* __restrict__ featsk,
                                              const float* __restrict__ S,
                                              const float* __restrict__ cnt,
                                              const float* __restrict__ nn1g,
                                              const float* __restrict__ nn1b,
                                              const float* __restrict__ eng,
                                              const float* __restrict__ enb,
                                              float* __restrict__ H0) {
    int n = blockIdx.x, tid = threadIdx.x;
    __shared__ float red[4];
    float x = featsk[(size_t)n * 768 + tid];
    float s = wave_sum64(x), ss = wave_sum64(x * x);
    if ((tid & 63) == 0) { red[(tid >> 6) * 2] = s; red[(tid >> 6) * 2 + 1] = ss; }
    __syncthreads();
    float S1 = red[0] + red[2], S2 = red[1] + red[3];
    float mean = S1 * (1.0f / 128.0f);
    float var = S2 * (1.0f / 128.0f) - mean * mean;
    float rstd = 1.0f / sqrtf(var + EPS);
    H0[(size_t)n * 160 + tid] = (x - mean) * rstd * nn1g[tid] + nn1b[tid];
    if (tid < 32) {
        float inv = 1.0f / fmaxf(cnt[n], 1.0f);
        float v = S[(size_t)n * 32 + tid] * inv;
        float s2 = v, q2 = v * v;
        #pragma unroll
        for (int off = 16; off > 0; off >>= 1) {
            s2 += __shfl_xor(s2, off, 64);
            q2 += __shfl_xor(q2, off, 64);
        }
        float m2 = s2 * (1.0f / 32.0f);
        float va = q2 * (1.0f / 32.0f) - m2 * m2;
        float rs = 1.0f / sqrtf(va + EPS);
        H0[(size_t)n * 160 + 128 + tid] = (v - m2) * rs * eng[tid] + enb[tid];
    }
}

// ---------------- LN + residual ----------------
__global__ __launch_bounds__(128) void k_ln_res(const float* __restrict__ H2,
                                                float* __restrict__ feats_all, int k,
                                                const float* __restrict__ g,
                                                const float* __restrict__ b) {
    int n = blockIdx.x, tid = threadIdx.x;
    __shared__ float red[4];
    float x = H2[(size_t)n * 128 + tid];
    float s = wave_sum64(x), ss = wave_sum64(x * x);
    if ((tid & 63) == 0) { red[(tid >> 6) * 2] = s; red[(tid >> 6) * 2 + 1] = ss; }
    __syncthreads();
    float S1 = red[0] + red[2], S2 = red[1] + red[3];
    float mean = S1 * (1.0f / 128.0f);
    float var = S2 * (1.0f / 128.0f) - mean * mean;
    float rstd = 1.0f / sqrtf(var + EPS);
    float v = (x - mean) * rstd * g[tid] + b[tid];
    float f = feats_all[(size_t)n * 768 + k * 128 + tid];
    feats_all[(size_t)n * 768 + (k + 1) * 128 + tid] = f + v;
}

// ---------------- graph pooling (batch sorted -> run-length accum) ----------------
__global__ __launch_bounds__(256) void k_pool(const float* __restrict__ F,
                                              const int* __restrict__ batch,
                                              float* __restrict__ G,
                                              float* __restrict__ cntg) {
    __shared__ int bL[32];
    int b0 = blockIdx.x * 32;
    int tid = threadIdx.x;
    int nmax = min(32, N_NODES - b0);
    if (nmax <= 0) return;
    if (tid < nmax) bL[tid] = batch[b0 + tid];
    __syncthreads();
    float accv = 0.f;
    int cur = -1;
    for (int i = 0; i < nmax; ++i) {
        int g = bL[i];
        if (g != cur) {
            if (cur >= 0) atomicAdd(&G[(size_t)cur * 256 + tid], accv);
            cur = g; accv = 0.f;
        }
        accv += F[(size_t)(b0 + i) * 256 + tid];
    }
    if (cur >= 0) atomicAdd(&G[(size_t)cur * 256 + tid], accv);
    if (tid == 0)
        for (int i = 0; i < nmax; ++i) atomicAdd(&cntg[bL[i]], 1.0f);
}

// ---------------- per-graph MLP head ----------------
__global__ __launch_bounds__(256) void k_graph(const float* __restrict__ G,
                                               const float* __restrict__ cntg,
                                               const float* __restrict__ g1W,
                                               const float* __restrict__ g1b,
                                               const float* __restrict__ g2W,
                                               const float* __restrict__ g2b,
                                               const float* __restrict__ g3W,
                                               const float* __restrict__ g3b,
                                               float* __restrict__ out) {
    __shared__ float X[256], Y[256], red[4];
    int g = blockIdx.x, tid = threadIdx.x;
    float inv = 1.0f / fmaxf(cntg[g], 1.0f);
    X[tid] = G[(size_t)g * 256 + tid] * inv;
    __syncthreads();
    float a = g1b[tid];
    for (int j = 0; j < 256; ++j) a = fmaf(X[j], g1W[(size_t)j * 256 + tid], a);
    Y[tid] = silu(a);
    __syncthreads();
    a = g2b[tid];
    for (int j = 0; j < 256; ++j) a = fmaf(Y[j], g2W[(size_t)j * 256 + tid], a);
    float z = silu(a);
    float p = z * g3W[tid];
    p = wave_sum64(p);
    if ((tid & 63) == 0) red[tid >> 6] = p;
    __syncthreads();
    if (tid == 0) out[g] = red[0] + red[1] + red[2] + red[3] + g3b[0];
}

extern "C" void kernel_launch(void* const* d_in, const int* in_sizes, int n_in,
                              void* d_out, int out_size, void* d_ws, size_t ws_size,
                              hipStream_t stream) {
    const int*   atomids = (const int*)d_in[0];
    const float* coords  = (const float*)d_in[1];
    const int*   eidx    = (const int*)d_in[2];
    const int*   batch   = (const int*)d_in[3];
    const float* emb_w   = (const float*)d_in[4];
    const float* eW1     = (const float*)d_in[5];
    const float* eb1     = (const float*)d_in[6];
    const float* eW2     = (const float*)d_in[7];
    const float* eb2     = (const float*)d_in[8];
    const float* en_g    = (const float*)d_in[9];
    const float* en_b    = (const float*)d_in[10];
    const float* nn1_g   = (const float*)d_in[11];
    const float* nn1_b   = (const float*)d_in[12];
    const float* nW1     = (const float*)d_in[13];
    const float* nb1     = (const float*)d_in[14];
    const float* nW2     = (const float*)d_in[15];
    const float* nb2     = (const float*)d_in[16];
    const float* nn2_g   = (const float*)d_in[17];
    const float* nn2_b   = (const float*)d_in[18];
    const float* f1W     = (const float*)d_in[19];
    const float* f1b     = (const float*)d_in[20];
    const float* f2W     = (const float*)d_in[21];
    const float* f2b     = (const float*)d_in[22];
    const float* f3W     = (const float*)d_in[23];
    const float* f3b     = (const float*)d_in[24];
    const float* g1W     = (const float*)d_in[25];
    const float* g1b     = (const float*)d_in[26];
    const float* g2W     = (const float*)d_in[27];
    const float* g2b     = (const float*)d_in[28];
    const float* g3W     = (const float*)d_in[29];
    const float* g3b     = (const float*)d_in[30];
    float* out = (float*)d_out;

    float* ws = (float*)d_ws;
    float* feats_all = ws;                        // [10000][768]
    float* d2g   = ws + 7680000;                  // [160000]
    float* Pab   = ws + 7840000;                  // [10000][1296]
    float* S     = ws + 20800000;                 // [10000][32]
    float* cnt   = ws + 21120000;                 // [10000]
    float* W1ab5 = ws + 21130000;                 // [5][128][1296]
    float* W1cp5 = ws + 21959440;                 // [5][65][768]
    float* b1p5  = ws + 22209040;                 // [5][768]
    float* W2p5  = ws + 22212880;                 // [5][768][32]
    float* feG   = ws + 22335760;                 // [12289][68]
    float* T     = ws + 23171412;                 // [12289][648]
    float* G     = ws + 31134684;                 // [64][256]
    float* cntg  = ws + 31151068;                 // [64]
    int*   histI = (int*)(ws + 31151132);         // [12304]
    int*   offs  = (int*)(ws + 31163436);         // [12304]
    int*   cursor= (int*)(ws + 31175740);         // [12304]
    int*   ssiP  = (int*)(ws + 31188044);         // [160000]
    int*   dsiP  = (int*)(ws + 31348044);         // [160000]
    int*   i0P   = (int*)(ws + 31508044);         // [160000]
    float* frP   = ws + 31668044;                 // [160000] (end ~31.83M floats = 127.3 MB)
    // node-phase temporaries overlay Pab (dead between phases; 12.96M floats available)
    float* H0 = Pab;                              // [10000][160]
    float* H1 = Pab + 1600000;                    // [10000][256]
    float* H2 = Pab + 4160000;                    // [10000][128]
    float* F1 = Pab;                              // [10000][256]
    float* F2 = Pab + 2560000;                    // [10000][256]
    float* F3 = Pab + 5120000;                    // [10000][256]

    k_embed<<<N_NODES, 128, 0, stream>>>(atomids, emb_w, feats_all);
    k_d2<<<(N_EDGES + 255) / 256, 256, 0, stream>>>(coords, eidx, d2g);
    hipMemsetAsync(cnt, 0, 10000 * sizeof(float), stream);
    k_cnt<<<(N_EDGES + 255) / 256, 256, 0, stream>>>(eidx, cnt);
    hipMemsetAsync(histI, 0, 12304 * sizeof(int), stream);
    k_hist<<<(N_EDGES + 255) / 256, 256, 0, stream>>>(d2g, histI);
    k_scan<<<1, 256, 0, stream>>>(histI, offs);
    k_copyi<<<(TROWS + 255) / 256, 256, 0, stream>>>(offs, cursor);
    k_scatter<<<(N_EDGES + 255) / 256, 256, 0, stream>>>(eidx, d2g, cursor,
                                                         ssiP, dsiP, i0P, frP);
    k_feg<<<(TROWS + 255) / 256, 256, 0, stream>>>(feG);
    k_w1ab5<<<dim3(648, 5), 256, 0, stream>>>(eW1, W1ab5);
    k_wpre5<<<dim3(294, 5), 256, 0, stream>>>(eW1, eb1, eW2, W1cp5, b1p5, W2p5);

    for (int k = 0; k < NK; ++k) {
        const float* eb2k = eb2 + (size_t)k * 32;
        const float* engk = en_g + (size_t)k * 32;
        const float* enbk = en_b + (size_t)k * 32;
        const float* nn1gk = nn1_g + (size_t)k * 128;
        const float* nn1bk = nn1_b + (size_t)k * 128;
        const float* nW1k = nW1 + (size_t)k * 160 * 256;
        const float* nb1k = nb1 + (size_t)k * 256;
        const float* nW2k = nW2 + (size_t)k * 256 * 128;
        const float* nb2k = nb2 + (size_t)k * 128;
        const float* nn2gk = nn2_g + (size_t)k * 128;
        const float* nn2bk = nn2_b + (size_t)k * 128;

        k_tab<<<(TROWS + 31) / 32, 256, 0, stream>>>(feG,
                                                     W1cp5 + (size_t)k * 65 * 768,
                                                     b1p5 + (size_t)k * 768, T);
        // MUST write all 1296 Pab columns (k_edge reads zero-padding up to col 1295)
        k_gemm<<<dim3(79, 11), 256, 0, stream>>>(feats_all + k * 128, 768,
                                                 W1ab5 + (size_t)k * 128 * 1296, 1296,
                                                 nullptr, Pab, 1296, N_NODES, 1296, 128, 0, 0);
        hipMemsetAsync(S, 0, (size_t)320000 * sizeof(float), stream);
        k_edge<<<N_EDGES / EPB, 256, 0, stream>>>(ssiP, dsiP, i0P, frP, T, Pab,
                                                  W2p5 + (size_t)k * 768 * 32,
                                                  eb2k, engk, enbk, S);
        k_prep<<<N_NODES, 128, 0, stream>>>(feats_all + k * 128, S, cnt,
                                            nn1gk, nn1bk, engk, enbk, H0);
        k_gemm<<<dim3(79, 2), 256, 0, stream>>>(H0, 160, nW1k, 256, nb1k, H1, 256,
                                                N_NODES, 256, 160, 0, 1);
        k_gemm<<<dim3(79, 1), 256, 0, stream>>>(H1, 256, nW2k, 128, nb2k, H2, 128,
                                                N_NODES, 128, 256, 0, 0);
        k_ln_res<<<N_NODES, 128, 0, stream>>>(H2, feats_all, k, nn2gk, nn2bk);
    }

    // final node MLP (F1/F2/F3 overlay Pab)
    k_gemm<<<dim3(79, 2), 256, 0, stream>>>(feats_all, 768, f1W, 256, f1b, F1, 256,
                                            N_NODES, 256, 768, 1, 1);
    k_gemm<<<dim3(79, 2), 256, 0, stream>>>(F1, 256, f2W, 256, f2b, F2, 256,
                                            N_NODES, 256, 256, 0, 1);
    k_gemm<<<dim3(79, 2), 256, 0, stream>>>(F2, 256, f3W, 256, f3b, F3, 256,
                                            N_NODES, 256, 256, 0, 1);

    hipMemsetAsync(G, 0, (size_t)(16384 + 64) * sizeof(float), stream);
    k_pool<<<313, 256, 0, stream>>>(F3, batch, G, cntg);
    k_graph<<<N_GRAPHS, 256, 0, stream>>>(G, cntg, g1W, g1b, g2W, g2b, g3W, g3b, out);
}

// Round 7
// 2973.443 us; speedup vs baseline: 1.3468x; 1.3468x over previous
//
#include <hip/hip_runtime.h>
#include <hip/hip_bf16.h>

#define N_NODES 10000
#define N_EDGES 160000
#define N_GRAPHS 64
#define NK 5
#define EPS 1e-5f
#define EPB 64           // edges per block (256 threads)
#define JP 648           // packed width for Pab halves
#define PSTRIDE 1296     // Pab row stride: [Pa 648 | Pb 648]
#define TCOLS 648        // table row width (642 -> 648)
#define TROWS 12289      // d2 grid [0,96], h=1/128
#define IMAX 12287

__device__ __forceinline__ float silu(float x) { return x / (1.0f + __expf(-x)); }
__device__ __forceinline__ float4 f4fma(float s, float4 w, float4 a) {
    a.x = fmaf(s, w.x, a.x); a.y = fmaf(s, w.y, a.y);
    a.z = fmaf(s, w.z, a.z); a.w = fmaf(s, w.w, a.w);
    return a;
}
__device__ __forceinline__ float wave_sum64(float v) {
    #pragma unroll
    for (int off = 32; off > 0; off >>= 1) v += __shfl_xor(v, off, 64);
    return v;
}

// ---------------- embedding ----------------
__global__ __launch_bounds__(128) void k_embed(const int* __restrict__ atomids,
                                               const float* __restrict__ emb_w,
                                               float* __restrict__ feats_all) {
    int n = blockIdx.x, tid = threadIdx.x;
    feats_all[(size_t)n * 768 + tid] = emb_w[(size_t)atomids[n] * 128 + tid];
}

// ---------------- per-edge squared distance ----------------
__global__ __launch_bounds__(256) void k_d2(const float* __restrict__ coords,
                                            const int* __restrict__ eidx,
                                            float* __restrict__ d2g) {
    int e = blockIdx.x * 256 + threadIdx.x;
    if (e >= N_EDGES) return;
    int s = eidx[e], d = eidx[N_EDGES + e];
    float dx = coords[s * 3 + 0] - coords[d * 3 + 0];
    float dy = coords[s * 3 + 1] - coords[d * 3 + 1];
    float dz = coords[s * 3 + 2] - coords[d * 3 + 2];
    d2g[e] = dx * dx + dy * dy + dz * dz;
}

// ---------------- in-degree (layer-invariant) ----------------
__global__ __launch_bounds__(256) void k_cnt(const int* __restrict__ eidx,
                                             float* __restrict__ cnt) {
    int e = blockIdx.x * 256 + threadIdx.x;
    if (e >= N_EDGES) return;
    atomicAdd(&cnt[eidx[N_EDGES + e]], 1.0f);
}

// ---------------- counting sort of edges by i0 (T-row index) ----------------
__global__ __launch_bounds__(256) void k_hist(const float* __restrict__ d2g,
                                              int* __restrict__ hist) {
    int e = blockIdx.x * 256 + threadIdx.x;
    if (e >= N_EDGES) return;
    int i0 = (int)(d2g[e] * 128.0f);
    if (i0 > IMAX) i0 = IMAX;
    atomicAdd(&hist[i0], 1);
}

__global__ __launch_bounds__(256) void k_scan(const int* __restrict__ hist,
                                              int* __restrict__ offs) {
    __shared__ int buf[256];
    __shared__ int carryS;
    int tid = threadIdx.x;
    if (tid == 0) carryS = 0;
    __syncthreads();
    for (int base = 0; base < TROWS; base += 256) {
        int v = (base + tid < TROWS) ? hist[base + tid] : 0;
        buf[tid] = v;
        __syncthreads();
        for (int off = 1; off < 256; off <<= 1) {
            int t = (tid >= off) ? buf[tid - off] : 0;
            __syncthreads();
            buf[tid] += t;
            __syncthreads();
        }
        if (base + tid < TROWS) offs[base + tid] = carryS + buf[tid] - v;  // exclusive
        __syncthreads();
        if (tid == 0) carryS += buf[255];
        __syncthreads();
    }
}

__global__ __launch_bounds__(256) void k_copyi(const int* __restrict__ a,
                                               int* __restrict__ b) {
    int i = blockIdx.x * 256 + threadIdx.x;
    if (i < TROWS) b[i] = a[i];
}

__global__ __launch_bounds__(256) void k_scatter(const int* __restrict__ eidx,
                                                 const float* __restrict__ d2g,
                                                 int* __restrict__ cursor,
                                                 int* __restrict__ ssiP,
                                                 int* __restrict__ dsiP,
                                                 int* __restrict__ i0P,
                                                 float* __restrict__ frP) {
    int e = blockIdx.x * 256 + threadIdx.x;
    if (e >= N_EDGES) return;
    float t = d2g[e] * 128.0f;
    int i0 = (int)t;
    if (i0 > IMAX) i0 = IMAX;
    float fr = t - (float)i0;
    int pos = atomicAdd(&cursor[i0], 1);
    ssiP[pos] = eidx[e];
    dsiP[pos] = eidx[N_EDGES + e];
    i0P[pos] = i0;
    frP[pos] = fr;
}

// ---------------- fourier features on the d2 GRID (once) ----------------
__global__ __launch_bounds__(256) void k_feg(float* __restrict__ feG) {  // [TROWS][68]
    int g = blockIdx.x * 256 + threadIdx.x;
    if (g >= TROWS) return;
    float d2v = (float)g * 0.0078125f;   // g / 128, exact
    float* o = feG + (size_t)g * 68;
    float sc = 1.0f;
    #pragma unroll
    for (int i = 0; i < 32; ++i) {
        float x = d2v * sc;
        o[i] = sinf(x);
        o[32 + i] = cosf(x);
        sc *= 0.5f;
    }
    o[64] = d2v;
}

// ---------------- per-layer q-table: T[g][j] = fe(g/128) @ W1c + b1 ----------------
__global__ __launch_bounds__(256) void k_tab(const float* __restrict__ feG,   // [TROWS][68]
                                             const float* __restrict__ W1cp,  // [65][768]
                                             const float* __restrict__ b1p,   // [768]
                                             float* __restrict__ T) {         // [TROWS][648]
    __shared__ float feGs[32 * 68];
    __shared__ float W1s[65 * 36];
    const int tid = threadIdx.x;
    const int g0 = blockIdx.x * 32;
    for (int idx = tid; idx < 32 * 17; idx += 256) {
        int r = idx / 17, c = idx - r * 17;
        int gi = g0 + r;
        float4 v = make_float4(0, 0, 0, 0);
        if (gi < TROWS) v = *(const float4*)(feG + (size_t)gi * 68 + 4 * c);
        *(float4*)&feGs[r * 68 + 4 * c] = v;
    }
    const int gt = tid >> 3, ct = tid & 7;
    for (int jc = 0; jc < TCOLS; jc += 32) {
        __syncthreads();
        for (int idx = tid; idx < 65 * 32; idx += 256) {
            int k = idx >> 5, j = idx & 31;
            W1s[k * 36 + j] = W1cp[(size_t)k * 768 + jc + j];
        }
        __syncthreads();
        int gj = jc + 4 * ct;
        float4 q = *(const float4*)(b1p + gj);
        #pragma unroll 5
        for (int k = 0; k < 65; ++k) {
            float f = feGs[gt * 68 + k];
            float4 w = *(const float4*)&W1s[k * 36 + 4 * ct];
            q = f4fma(f, w, q);
        }
        int g = g0 + gt;
        if (g < TROWS && gj < TCOLS)
            *(float4*)(T + (size_t)g * TCOLS + gj) = q;
    }
}

// ---------------- W1ab prestage, all 5 layers: [5][128][1296] = [W1a|0|W1b|0] packed ----------------
__global__ __launch_bounds__(256) void k_w1ab5(const float* __restrict__ eW1,
                                               float* __restrict__ W1ab5) {
    int k = blockIdx.y;
    const float* W1 = eW1 + (size_t)k * 321 * 642;
    float* W1ab = W1ab5 + (size_t)k * 128 * 1296;
    int idx = blockIdx.x * 256 + threadIdx.x;
    if (idx >= 128 * 1296) return;
    int r = idx / 1296;
    int j = idx - r * 1296;
    float v = 0.f;
    if (j < 642) v = W1[(size_t)r * 642 + j];
    else if (j >= 648 && j < 1290) v = W1[(size_t)(128 + r) * 642 + (j - 648)];
    W1ab[idx] = v;
}

// ---------------- padded edge-weight prestage (all 5 layers) ----------------
__global__ __launch_bounds__(256) void k_wpre5(const float* __restrict__ eW1,
                                               const float* __restrict__ eb1,
                                               const float* __restrict__ eW2,
                                               float* __restrict__ W1cp5,   // [5][65][768]
                                               float* __restrict__ b1p5,    // [5][768]
                                               float* __restrict__ W2p5) {  // [5][768][32]
    int k = blockIdx.y;
    const float* W1 = eW1 + (size_t)k * 321 * 642;
    const float* b1 = eb1 + (size_t)k * 642;
    const float* W2 = eW2 + (size_t)k * 642 * 32;
    float* W1cp = W1cp5 + (size_t)k * 65 * 768;
    float* b1p  = b1p5 + (size_t)k * 768;
    float* W2p  = W2p5 + (size_t)k * 768 * 32;
    int idx = blockIdx.x * 256 + threadIdx.x;
    if (idx < 65 * 768) {
        int r = idx / 768, j = idx - r * 768;
        W1cp[idx] = (j < 642) ? W1[(size_t)(256 + r) * 642 + j] : 0.f;
    } else if (idx < 65 * 768 + 768) {
        int j = idx - 65 * 768;
        b1p[j] = (j < 642) ? b1[j] : 0.f;
    } else if (idx < 65 * 768 + 768 + 768 * 32) {
        int t = idx - (65 * 768 + 768);
        int j = t >> 5, c = t & 31;
        W2p[t] = (j < 642) ? W2[(size_t)j * 32 + c] : 0.f;
    }
}

// ---------------- fp32 GEMM: C = act(actA(A)[M][K] @ B[K][N] + bias) ----------------
// Pipelined: next k-tile's global loads issued BEFORE the FMA loop (ra/rb = 32 VGPR,
// small enough to stay register-resident; v5 showed bigger prefetch sets spill).
__global__ __launch_bounds__(256) void k_gemm(const float* __restrict__ A, int lda,
                                              const float* __restrict__ B, int ldb,
                                              const float* __restrict__ bias,
                                              float* __restrict__ C, int ldc,
                                              int M, int N, int K, int siluA, int siluOut) {
    __shared__ float As[32 * 132];
    __shared__ float Bs[32 * 132];
    const int tid = threadIdx.x;
    const int m0 = blockIdx.x * 128, n0 = blockIdx.y * 128;
    const int tm = tid >> 4, tn = tid & 15;

    float4 acc[8][2];
    #pragma unroll
    for (int r = 0; r < 8; ++r) { acc[r][0] = make_float4(0,0,0,0); acc[r][1] = make_float4(0,0,0,0); }

    float4 ra[4], rb[4];

#define GLOAD(kc_) do { \
    _Pragma("unroll") \
    for (int i_ = 0; i_ < 4; ++i_) { \
        int idx_ = tid + i_ * 256; \
        int m_ = idx_ >> 3, kq_ = idx_ & 7; \
        int gm_ = m0 + m_; \
        int cm_ = (gm_ < M) ? gm_ : (M - 1); \
        float4 a_ = *(const float4*)(A + (size_t)cm_ * lda + (kc_) + 4 * kq_); \
        if (gm_ >= M) a_ = make_float4(0,0,0,0); \
        ra[i_] = a_; \
    } \
    _Pragma("unroll") \
    for (int i_ = 0; i_ < 4; ++i_) { \
        int idx_ = tid + i_ * 256; \
        int r_ = idx_ >> 5, cq_ = idx_ & 31; \
        int gn_ = n0 + 4 * cq_; \
        float4 b_ = make_float4(0,0,0,0); \
        if (gn_ < N) b_ = *(const float4*)(B + (size_t)((kc_) + r_) * ldb + gn_); \
        rb[i_] = b_; \
    } \
} while (0)

    GLOAD(0);

    for (int kc = 0; kc < K; kc += 32) {
        // regs -> LDS (consume ra/rb from the prefetch)
        #pragma unroll
        for (int i = 0; i < 4; ++i) {
            int idx = tid + i * 256;
            int m = idx >> 3, kq = idx & 7;
            float4 a = ra[i];
            if (siluA) { a.x = silu(a.x); a.y = silu(a.y); a.z = silu(a.z); a.w = silu(a.w); }
            As[(4 * kq + 0) * 132 + m] = a.x;
            As[(4 * kq + 1) * 132 + m] = a.y;
            As[(4 * kq + 2) * 132 + m] = a.z;
            As[(4 * kq + 3) * 132 + m] = a.w;
        }
        #pragma unroll
        for (int i = 0; i < 4; ++i) {
            int idx = tid + i * 256;
            int r = idx >> 5, cq = idx & 31;
            *(float4*)&Bs[r * 132 + 4 * cq] = rb[i];
        }
        __syncthreads();
        if (kc + 32 < K) GLOAD(kc + 32);   // in flight during FMA below
        #pragma unroll 4
        for (int kk = 0; kk < 32; ++kk) {
            float4 a0 = *(const float4*)&As[kk * 132 + 8 * tm];
            float4 a1 = *(const float4*)&As[kk * 132 + 8 * tm + 4];
            float4 b0 = *(const float4*)&Bs[kk * 132 + 4 * tn];
            float4 b1 = *(const float4*)&Bs[kk * 132 + 64 + 4 * tn];
            acc[0][0] = f4fma(a0.x, b0, acc[0][0]); acc[0][1] = f4fma(a0.x, b1, acc[0][1]);
            acc[1][0] = f4fma(a0.y, b0, acc[1][0]); acc[1][1] = f4fma(a0.y, b1, acc[1][1]);
            acc[2][0] = f4fma(a0.z, b0, acc[2][0]); acc[2][1] = f4fma(a0.z, b1, acc[2][1]);
            acc[3][0] = f4fma(a0.w, b0, acc[3][0]); acc[3][1] = f4fma(a0.w, b1, acc[3][1]);
            acc[4][0] = f4fma(a1.x, b0, acc[4][0]); acc[4][1] = f4fma(a1.x, b1, acc[4][1]);
            acc[5][0] = f4fma(a1.y, b0, acc[5][0]); acc[5][1] = f4fma(a1.y, b1, acc[5][1]);
            acc[6][0] = f4fma(a1.z, b0, acc[6][0]); acc[6][1] = f4fma(a1.z, b1, acc[6][1]);
            acc[7][0] = f4fma(a1.w, b0, acc[7][0]); acc[7][1] = f4fma(a1.w, b1, acc[7][1]);
        }
        __syncthreads();
    }
#undef GLOAD

    const int gnl = n0 + 4 * tn, gnh = n0 + 64 + 4 * tn;
    #pragma unroll
    for (int r = 0; r < 8; ++r) {
        int gm = m0 + 8 * tm + r;
        if (gm >= M) continue;
        float4 v0 = acc[r][0], v1 = acc[r][1];
        if (gnl < N) {
            if (bias) { v0.x += bias[gnl+0]; v0.y += bias[gnl+1]; v0.z += bias[gnl+2]; v0.w += bias[gnl+3]; }
            if (siluOut) { v0.x = silu(v0.x); v0.y = silu(v0.y); v0.z = silu(v0.z); v0.w = silu(v0.w); }
            *(float4*)&C[(size_t)gm * ldc + gnl] = v0;
        }
        if (gnh < N) {
            if (bias) { v1.x += bias[gnh+0]; v1.y += bias[gnh+1]; v1.z += bias[gnh+2]; v1.w += bias[gnh+3]; }
            if (siluOut) { v1.x = silu(v1.x); v1.y = silu(v1.y); v1.z = silu(v1.z); v1.w = silu(v1.w); }
            *(float4*)&C[(size_t)gm * ldc + gnh] = v1;
        }
    }
}

// ---------------- fused edge kernel v6: v3 structure + single W2s buffer (occupancy) ----------------
// v5 post-mortem: 40-float4 prefetch SPILLED to scratch (WRITE_SIZE 160->583MB, dur 278->502).
// ILP-deepening is a dead end on this allocator; the untried lever is TLP.
// v6 = v3 reverted, with the W2s double-buffer removed: writes already sit in the bA->bB
// barrier window and reads in bB->bA, so a single buffer has IDENTICAL ordering guarantees
// (double-buffering bought nothing). LDS 37.9 -> 28.7 KB => 5 blocks/CU (was 4), more
// independent waves to hide the Pab gather latency. launch_bounds(256,4): VGPR 84 < 128 cap.
// Same data, same FMA order -> bit-identical output.
__global__ __launch_bounds__(256, 4) void k_edge(const int* __restrict__ ssiP,
                                                 const int* __restrict__ dsiP,
                                                 const int* __restrict__ i0P,
                                                 const float* __restrict__ frP,
                                                 const float* __restrict__ T,     // [TROWS][648]
                                                 const float* __restrict__ Pab,   // [N_NODES][1296]
                                                 const float* __restrict__ W2p,   // [768][32]
                                                 const float* __restrict__ b2,
                                                 const float* __restrict__ eng,
                                                 const float* __restrict__ enb,
                                                 float* __restrict__ S) {
    __shared__ float Zs[64 * 70];        // 17920 B; overlaid by m2s[64][36] in epilogue
    __shared__ float W2s[64 * 36];       // single-buffered W2 chunk, 9216 B
    __shared__ int dsi[EPB], ssi[EPB], i0s[EPB];
    __shared__ float frs[EPB];
    __shared__ float cpar[96];

    const int tid = threadIdx.x;
    // XCD-chunked bijective swizzle (nwg=2500, 8 XCDs: q=312, r=4 -> first 4 XCDs 313 blocks)
    const int bid = blockIdx.x;
    const int xcd = bid & 7, bpos = bid >> 3;
    const int wg = (xcd < 4) ? xcd * 313 + bpos : 1252 + (xcd - 4) * 312 + bpos;
    const int eb = wg * EPB;
    const int lane = tid & 31;           // edge-pair index (both phases)
    const int grp = tid >> 5;            // col group: phase-1 8 cols, phase-2 4 out-cols

    if (tid < EPB) {
        ssi[tid] = ssiP[eb + tid];
        dsi[tid] = dsiP[eb + tid];
        i0s[tid] = i0P[eb + tid];
        frs[tid] = frP[eb + tid];
    }
    if (tid < 32) cpar[tid] = b2[tid];
    else if (tid < 64) cpar[tid] = eng[tid - 32];
    else if (tid < 96) cpar[tid] = enb[tid - 64];
    __syncthreads();

    int dsr[2], ssr[2], i0r[2];
    float frr[2];
    #pragma unroll
    for (int i = 0; i < 2; ++i) {
        int e = 2 * lane + i;
        dsr[i] = dsi[e]; ssr[i] = ssi[e];
        i0r[i] = i0s[e]; frr[i] = frs[e];
    }

    float4 accm[2];
    accm[0] = make_float4(0,0,0,0);
    accm[1] = make_float4(0,0,0,0);

    // prefetch registers (next chunk's T rows, Pab rows, W2 chunk)
    float4 rA0[2], rA1[2], rB0[2], rB1[2];
    float4 rP0[2], rP1[2], rQ0[2], rQ1[2];
    float4 rw0, rw1;

#define PREFETCH(cn) do { \
    const int colb_ = 64 * (cn) + 8 * grp; \
    if (colb_ < TCOLS) { \
        _Pragma("unroll") \
        for (int i_ = 0; i_ < 2; ++i_) { \
            const float* t0_ = T + (size_t)i0r[i_] * TCOLS + colb_; \
            rA0[i_] = *(const float4*)t0_; \
            rA1[i_] = *(const float4*)(t0_ + 4); \
            rB0[i_] = *(const float4*)(t0_ + TCOLS); \
            rB1[i_] = *(const float4*)(t0_ + TCOLS + 4); \
            const float* pr_ = Pab + (size_t)dsr[i_] * PSTRIDE + colb_; \
            const float* qr_ = Pab + (size_t)ssr[i_] * PSTRIDE + JP + colb_; \
            rP0[i_] = *(const float4*)pr_; rP1[i_] = *(const float4*)(pr_ + 4); \
            rQ0[i_] = *(const float4*)qr_; rQ1[i_] = *(const float4*)(qr_ + 4); \
        } \
    } \
    const float* ws_ = W2p + (size_t)(64 * (cn)) * 32 + 8 * tid; \
    rw0 = *(const float4*)ws_; rw1 = *(const float4*)(ws_ + 4); \
} while (0)

    PREFETCH(0);

    for (int ch = 0; ch < 11; ++ch) {
        const int colb = 64 * ch + 8 * grp;

        // ---- compute qa from prefetched regs (vmcnt wait lands here, post-FMA) ----
        float qa[2][8];
        if (colb < TCOLS) {
            #pragma unroll
            for (int i = 0; i < 2; ++i) {
                float f = frr[i];
                qa[i][0] = silu(fmaf(f, rB0[i].x - rA0[i].x, rA0[i].x) + rP0[i].x + rQ0[i].x);
                qa[i][1] = silu(fmaf(f, rB0[i].y - rA0[i].y, rA0[i].y) + rP0[i].y + rQ0[i].y);
                qa[i][2] = silu(fmaf(f, rB0[i].z - rA0[i].z, rA0[i].z) + rP0[i].z + rQ0[i].z);
                qa[i][3] = silu(fmaf(f, rB0[i].w - rA0[i].w, rA0[i].w) + rP0[i].w + rQ0[i].w);
                qa[i][4] = silu(fmaf(f, rB1[i].x - rA1[i].x, rA1[i].x) + rP1[i].x + rQ1[i].x);
                qa[i][5] = silu(fmaf(f, rB1[i].y - rA1[i].y, rA1[i].y) + rP1[i].y + rQ1[i].y);
                qa[i][6] = silu(fmaf(f, rB1[i].z - rA1[i].z, rA1[i].z) + rP1[i].z + rQ1[i].z);
                qa[i][7] = silu(fmaf(f, rB1[i].w - rA1[i].w, rA1[i].w) + rP1[i].w + rQ1[i].w);
            }
        } else {
            #pragma unroll
            for (int i = 0; i < 2; ++i)
                #pragma unroll
                for (int c = 0; c < 8; ++c) qa[i][c] = 0.f;
        }

        __syncthreads();   // bA: previous FMA done -> Zs + W2s free for overwrite

        // Zs write: rows j = 8*grp..8*grp+7, col pair 2*lane
        #pragma unroll
        for (int jj = 0; jj < 8; ++jj) {
            float2 z2;
            z2.x = qa[0][jj]; z2.y = qa[1][jj];
            *(float2*)&Zs[(8 * grp + jj) * 70 + 2 * lane] = z2;
        }
        // W2s write from prefetched regs (rows 64ch..64ch+63 of W2p)
        {
            int wrow = tid >> 2;
            int wc0 = (2 * tid) & 7;
            *(float4*)&W2s[wrow * 36 + 4 * wc0] = rw0;
            *(float4*)&W2s[wrow * 36 + 4 * (wc0 + 1)] = rw1;
        }

        __syncthreads();   // bB: Zs + W2s published

        if (ch < 10) PREFETCH(ch + 1);   // issued BEFORE FMA -> in flight during it

        #pragma unroll 8
        for (int kk = 0; kk < 64; ++kk) {
            float2 z2 = *(const float2*)&Zs[kk * 70 + 2 * lane];
            float4 w4 = *(const float4*)&W2s[kk * 36 + 4 * grp];
            accm[0] = f4fma(z2.x, w4, accm[0]);
            accm[1] = f4fma(z2.y, w4, accm[1]);
        }
    }
#undef PREFETCH

    // ---- epilogue: m2 = silu(accm + b2), LN, scatter ----
    __syncthreads();                 // FMA(10) done -> Zs reusable as m2s
    float* m2s = Zs;
    {
        float4 bb2 = *(const float4*)&cpar[4 * grp];
        #pragma unroll
        for (int i = 0; i < 2; ++i) {
            int e = 2 * lane + i;
            float4 o;
            o.x = silu(accm[i].x + bb2.x);
            o.y = silu(accm[i].y + bb2.y);
            o.z = silu(accm[i].z + bb2.z);
            o.w = silu(accm[i].w + bb2.w);
            *(float4*)&m2s[e * 36 + 4 * grp] = o;
        }
    }
    __syncthreads();
    {
        // 4 threads per edge: thread (e = tid>>2, q = tid&3) handles cols 8q..8q+7
        int e = tid >> 2, q = tid & 3;
        float4 v0 = *(const float4*)&m2s[e * 36 + 8 * q];
        float4 v1 = *(const float4*)&m2s[e * 36 + 8 * q + 4];
        float s  = v0.x + v0.y + v0.z + v0.w + v1.x + v1.y + v1.z + v1.w;
        float ss = v0.x*v0.x + v0.y*v0.y + v0.z*v0.z + v0.w*v0.w
                 + v1.x*v1.x + v1.y*v1.y + v1.z*v1.z + v1.w*v1.w;
        s  += __shfl_xor(s, 1, 64);  ss += __shfl_xor(ss, 1, 64);
        s  += __shfl_xor(s, 2, 64);  ss += __shfl_xor(ss, 2, 64);
        float mean = s * 0.03125f;
        float var = ss * 0.03125f - mean * mean;
        float rstd = 1.0f / sqrtf(var + EPS);
        int d = dsi[e];
        float* Sp = S + (size_t)d * 32 + 8 * q;
        const float* gg = cpar + 32 + 8 * q;
        const float* bbv = cpar + 64 + 8 * q;
        float vv[8] = {v0.x, v0.y, v0.z, v0.w, v1.x, v1.y, v1.z, v1.w};
        #pragma unroll
        for (int c = 0; c < 8; ++c)
            atomicAdd(&Sp[c], (vv[c] - mean) * rstd * gg[c] + bbv[c]);
    }
}

// ---------------- node prep: H0 = [LN(feats) | LN(S/cnt)] ----------------
__global__ __launch_bounds__(128) void k_prep(const float* __restrict__ featsk,
                                              const float* __restrict__ S,
                                              const float* __restrict__ cnt,
                                              const float* __restrict__ nn1g,
                                              const float* __restrict__ nn1b,
                                              const float* __restrict__ eng,
                                              const float* __restrict__ enb,
                                              float* __restrict__ H0) {
    int n = blockIdx.x, tid = threadIdx.x;
    __shared__ float red[4];
    float x = featsk[(size_t)n * 768 + tid];
    float s = wave_sum64(x), ss = wave_sum64(x * x);
    if ((tid & 63) == 0) { red[(tid >> 6) * 2] = s; red[(tid >> 6) * 2 + 1] = ss; }
    __syncthreads();
    float S1 = red[0] + red[2], S2 = red[1] + red[3];
    float mean = S1 * (1.0f / 128.0f);
    float var = S2 * (1.0f / 128.0f) - mean * mean;
    float rstd = 1.0f / sqrtf(var + EPS);
    H0[(size_t)n * 160 + tid] = (x - mean) * rstd * nn1g[tid] + nn1b[tid];
    if (tid < 32) {
        float inv = 1.0f / fmaxf(cnt[n], 1.0f);
        float v = S[(size_t)n * 32 + tid] * inv;
        float s2 = v, q2 = v * v;
        #pragma unroll
        for (int off = 16; off > 0; off >>= 1) {
            s2 += __shfl_xor(s2, off, 64);
            q2 += __shfl_xor(q2, off, 64);
        }
        float m2 = s2 * (1.0f / 32.0f);
        float va = q2 * (1.0f / 32.0f) - m2 * m2;
        float rs = 1.0f / sqrtf(va + EPS);
        H0[(size_t)n * 160 + 128 + tid] = (v - m2) * rs * eng[tid] + enb[tid];
    }
}

// ---------------- LN + residual ----------------
__global__ __launch_bounds__(128) void k_ln_res(const float* __restrict__ H2,
                                                float* __restrict__ feats_all, int k,
                                                const float* __restrict__ g,
                                                const float* __restrict__ b) {
    int n = blockIdx.x, tid = threadIdx.x;
    __shared__ float red[4];
    float x = H2[(size_t)n * 128 + tid];
    float s = wave_sum64(x), ss = wave_sum64(x * x);
    if ((tid & 63) == 0) { red[(tid >> 6) * 2] = s; red[(tid >> 6) * 2 + 1] = ss; }
    __syncthreads();
    float S1 = red[0] + red[2], S2 = red[1] + red[3];
    float mean = S1 * (1.0f / 128.0f);
    float var = S2 * (1.0f / 128.0f) - mean * mean;
    float rstd = 1.0f / sqrtf(var + EPS);
    float v = (x - mean) * rstd * g[tid] + b[tid];
    float f = feats_all[(size_t)n * 768 + k * 128 + tid];
    feats_all[(size_t)n * 768 + (k + 1) * 128 + tid] = f + v;
}

// ---------------- graph pooling (batch sorted -> run-length accum) ----------------
__global__ __launch_bounds__(256) void k_pool(const float* __restrict__ F,
                                              const int* __restrict__ batch,
                                              float* __restrict__ G,
                                              float* __restrict__ cntg) {
    __shared__ int bL[32];
    int b0 = blockIdx.x * 32;
    int tid = threadIdx.x;
    int nmax = min(32, N_NODES - b0);
    if (nmax <= 0) return;
    if (tid < nmax) bL[tid] = batch[b0 + tid];
    __syncthreads();
    float accv = 0.f;
    int cur = -1;
    for (int i = 0; i < nmax; ++i) {
        int g = bL[i];
        if (g != cur) {
            if (cur >= 0) atomicAdd(&G[(size_t)cur * 256 + tid], accv);
            cur = g; accv = 0.f;
        }
        accv += F[(size_t)(b0 + i) * 256 + tid];
    }
    if (cur >= 0) atomicAdd(&G[(size_t)cur * 256 + tid], accv);
    if (tid == 0)
        for (int i = 0; i < nmax; ++i) atomicAdd(&cntg[bL[i]], 1.0f);
}

// ---------------- per-graph MLP head ----------------
__global__ __launch_bounds__(256) void k_graph(const float* __restrict__ G,
                                               const float* __restrict__ cntg,
                                               const float* __restrict__ g1W,
                                               const float* __restrict__ g1b,
                                               const float* __restrict__ g2W,
                                               const float* __restrict__ g2b,
                                               const float* __restrict__ g3W,
                                               const float* __restrict__ g3b,
                                               float* __restrict__ out) {
    __shared__ float X[256], Y[256], red[4];
    int g = blockIdx.x, tid = threadIdx.x;
    float inv = 1.0f / fmaxf(cntg[g], 1.0f);
    X[tid] = G[(size_t)g * 256 + tid] * inv;
    __syncthreads();
    float a = g1b[tid];
    for (int j = 0; j < 256; ++j) a = fmaf(X[j], g1W[(size_t)j * 256 + tid], a);
    Y[tid] = silu(a);
    __syncthreads();
    a = g2b[tid];
    for (int j = 0; j < 256; ++j) a = fmaf(Y[j], g2W[(size_t)j * 256 + tid], a);
    float z = silu(a);
    float p = z * g3W[tid];
    p = wave_sum64(p);
    if ((tid & 63) == 0) red[tid >> 6] = p;
    __syncthreads();
    if (tid == 0) out[g] = red[0] + red[1] + red[2] + red[3] + g3b[0];
}

extern "C" void kernel_launch(void* const* d_in, const int* in_sizes, int n_in,
                              void* d_out, int out_size, void* d_ws, size_t ws_size,
                              hipStream_t stream) {
    const int*   atomids = (const int*)d_in[0];
    const float* coords  = (const float*)d_in[1];
    const int*   eidx    = (const int*)d_in[2];
    const int*   batch   = (const int*)d_in[3];
    const float* emb_w   = (const float*)d_in[4];
    const float* eW1     = (const float*)d_in[5];
    const float* eb1     = (const float*)d_in[6];
    const float* eW2     = (const float*)d_in[7];
    const float* eb2     = (const float*)d_in[8];
    const float* en_g    = (const float*)d_in[9];
    const float* en_b    = (const float*)d_in[10];
    const float* nn1_g   = (const float*)d_in[11];
    const float* nn1_b   = (const float*)d_in[12];
    const float* nW1     = (const float*)d_in[13];
    const float* nb1     = (const float*)d_in[14];
    const float* nW2     = (const float*)d_in[15];
    const float* nb2     = (const float*)d_in[16];
    const float* nn2_g   = (const float*)d_in[17];
    const float* nn2_b   = (const float*)d_in[18];
    const float* f1W     = (const float*)d_in[19];
    const float* f1b     = (const float*)d_in[20];
    const float* f2W     = (const float*)d_in[21];
    const float* f2b     = (const float*)d_in[22];
    const float* f3W     = (const float*)d_in[23];
    const float* f3b     = (const float*)d_in[24];
    const float* g1W     = (const float*)d_in[25];
    const float* g1b     = (const float*)d_in[26];
    const float* g2W     = (const float*)d_in[27];
    const float* g2b     = (const float*)d_in[28];
    const float* g3W     = (const float*)d_in[29];
    const float* g3b     = (const float*)d_in[30];
    float* out = (float*)d_out;

    float* ws = (float*)d_ws;
    float* feats_all = ws;                        // [10000][768]
    float* d2g   = ws + 7680000;                  // [160000]
    float* Pab   = ws + 7840000;                  // [10000][1296]
    float* S     = ws + 20800000;                 // [10000][32]
    float* cnt   = ws + 21120000;                 // [10000]
    float* W1ab5 = ws + 21130000;                 // [5][128][1296]
    float* W1cp5 = ws + 21959440;                 // [5][65][768]
    float* b1p5  = ws + 22209040;                 // [5][768]
    float* W2p5  = ws + 22212880;                 // [5][768][32]
    float* feG   = ws + 22335760;                 // [12289][68]
    float* T     = ws + 23171412;                 // [12289][648]
    float* G     = ws + 31134684;                 // [64][256]
    float* cntg  = ws + 31151068;                 // [64]
    int*   histI = (int*)(ws + 31151132);         // [12304]
    int*   offs  = (int*)(ws + 31163436);         // [12304]
    int*   cursor= (int*)(ws + 31175740);         // [12304]
    int*   ssiP  = (int*)(ws + 31188044);         // [160000]
    int*   dsiP  = (int*)(ws + 31348044);         // [160000]
    int*   i0P   = (int*)(ws + 31508044);         // [160000]
    float* frP   = ws + 31668044;                 // [160000] (end ~31.83M floats = 127.3 MB)
    // node-phase temporaries overlay Pab (dead between phases; 12.96M floats available)
    float* H0 = Pab;                              // [10000][160]
    float* H1 = Pab + 1600000;                    // [10000][256]
    float* H2 = Pab + 4160000;                    // [10000][128]
    float* F1 = Pab;                              // [10000][256]
    float* F2 = Pab + 2560000;                    // [10000][256]
    float* F3 = Pab + 5120000;                    // [10000][256]

    k_embed<<<N_NODES, 128, 0, stream>>>(atomids, emb_w, feats_all);
    k_d2<<<(N_EDGES + 255) / 256, 256, 0, stream>>>(coords, eidx, d2g);
    hipMemsetAsync(cnt, 0, 10000 * sizeof(float), stream);
    k_cnt<<<(N_EDGES + 255) / 256, 256, 0, stream>>>(eidx, cnt);
    hipMemsetAsync(histI, 0, 12304 * sizeof(int), stream);
    k_hist<<<(N_EDGES + 255) / 256, 256, 0, stream>>>(d2g, histI);
    k_scan<<<1, 256, 0, stream>>>(histI, offs);
    k_copyi<<<(TROWS + 255) / 256, 256, 0, stream>>>(offs, cursor);
    k_scatter<<<(N_EDGES + 255) / 256, 256, 0, stream>>>(eidx, d2g, cursor,
                                                         ssiP, dsiP, i0P, frP);
    k_feg<<<(TROWS + 255) / 256, 256, 0, stream>>>(feG);
    k_w1ab5<<<dim3(648, 5), 256, 0, stream>>>(eW1, W1ab5);
    k_wpre5<<<dim3(294, 5), 256, 0, stream>>>(eW1, eb1, eW2, W1cp5, b1p5, W2p5);

    for (int k = 0; k < NK; ++k) {
        const float* eb2k = eb2 + (size_t)k * 32;
        const float* engk = en_g + (size_t)k * 32;
        const float* enbk = en_b + (size_t)k * 32;
        const float* nn1gk = nn1_g + (size_t)k * 128;
        const float* nn1bk = nn1_b + (size_t)k * 128;
        const float* nW1k = nW1 + (size_t)k * 160 * 256;
        const float* nb1k = nb1 + (size_t)k * 256;
        const float* nW2k = nW2 + (size_t)k * 256 * 128;
        const float* nb2k = nb2 + (size_t)k * 128;
        const float* nn2gk = nn2_g + (size_t)k * 128;
        const float* nn2bk = nn2_b + (size_t)k * 128;

        k_tab<<<(TROWS + 31) / 32, 256, 0, stream>>>(feG,
                                                     W1cp5 + (size_t)k * 65 * 768,
                                                     b1p5 + (size_t)k * 768, T);
        // MUST write all 1296 Pab columns (k_edge reads zero-padding up to col 1295)
        k_gemm<<<dim3(79, 11), 256, 0, stream>>>(feats_all + k * 128, 768,
                                                 W1ab5 + (size_t)k * 128 * 1296, 1296,
                                                 nullptr, Pab, 1296, N_NODES, 1296, 128, 0, 0);
        hipMemsetAsync(S, 0, (size_t)320000 * sizeof(float), stream);
        k_edge<<<N_EDGES / EPB, 256, 0, stream>>>(ssiP, dsiP, i0P, frP, T, Pab,
                                                  W2p5 + (size_t)k * 768 * 32,
                                                  eb2k, engk, enbk, S);
        k_prep<<<N_NODES, 128, 0, stream>>>(feats_all + k * 128, S, cnt,
                                            nn1gk, nn1bk, engk, enbk, H0);
        k_gemm<<<dim3(79, 2), 256, 0, stream>>>(H0, 160, nW1k, 256, nb1k, H1, 256,
                                                N_NODES, 256, 160, 0, 1);
        k_gemm<<<dim3(79, 1), 256, 0, stream>>>(H1, 256, nW2k, 128, nb2k, H2, 128,
                                                N_NODES, 128, 256, 0, 0);
        k_ln_res<<<N_NODES, 128, 0, stream>>>(H2, feats_all, k, nn2gk, nn2bk);
    }

    // final node MLP (F1/F2/F3 overlay Pab)
    k_gemm<<<dim3(79, 2), 256, 0, stream>>>(feats_all, 768, f1W, 256, f1b, F1, 256,
                                            N_NODES, 256, 768, 1, 1);
    k_gemm<<<dim3(79, 2), 256, 0, stream>>>(F1, 256, f2W, 256, f2b, F2, 256,
                                            N_NODES, 256, 256, 0, 1);
    k_gemm<<<dim3(79, 2), 256, 0, stream>>>(F2, 256, f3W, 256, f3b, F3, 256,
                                            N_NODES, 256, 256, 0, 1);

    hipMemsetAsync(G, 0, (size_t)(16384 + 64) * sizeof(float), stream);
    k_pool<<<313, 256, 0, stream>>>(F3, batch, G, cntg);
    k_graph<<<N_GRAPHS, 256, 0, stream>>>(G, cntg, g1W, g1b, g2W, g2b, g3W, g3b, out);
}

// Round 8
// 2826.021 us; speedup vs baseline: 1.4170x; 1.0522x over previous
//
#include <hip/hip_runtime.h>
#include <hip/hip_bf16.h>

#define N_NODES 10000
#define N_EDGES 160000
#define N_GRAPHS 64
#define NK 5
#define EPS 1e-5f
#define EPB 64           // edges per block (256 threads)
#define JP 648           // packed width for Pab halves
#define PSTRIDE 1296     // Pab row stride: [Pa 648 | Pb 648]
#define TCOLS 648        // table row width (642 -> 648)
#define TROWS 12289      // d2 grid [0,96], h=1/128
#define IMAX 12287

__device__ __forceinline__ float silu(float x) { return x / (1.0f + __expf(-x)); }
__device__ __forceinline__ float4 f4fma(float s, float4 w, float4 a) {
    a.x = fmaf(s, w.x, a.x); a.y = fmaf(s, w.y, a.y);
    a.z = fmaf(s, w.z, a.z); a.w = fmaf(s, w.w, a.w);
    return a;
}
__device__ __forceinline__ float wave_sum64(float v) {
    #pragma unroll
    for (int off = 32; off > 0; off >>= 1) v += __shfl_xor(v, off, 64);
    return v;
}

// ---------------- embedding ----------------
__global__ __launch_bounds__(128) void k_embed(const int* __restrict__ atomids,
                                               const float* __restrict__ emb_w,
                                               float* __restrict__ feats_all) {
    int n = blockIdx.x, tid = threadIdx.x;
    feats_all[(size_t)n * 768 + tid] = emb_w[(size_t)atomids[n] * 128 + tid];
}

// ---------------- per-edge squared distance ----------------
__global__ __launch_bounds__(256) void k_d2(const float* __restrict__ coords,
                                            const int* __restrict__ eidx,
                                            float* __restrict__ d2g) {
    int e = blockIdx.x * 256 + threadIdx.x;
    if (e >= N_EDGES) return;
    int s = eidx[e], d = eidx[N_EDGES + e];
    float dx = coords[s * 3 + 0] - coords[d * 3 + 0];
    float dy = coords[s * 3 + 1] - coords[d * 3 + 1];
    float dz = coords[s * 3 + 2] - coords[d * 3 + 2];
    d2g[e] = dx * dx + dy * dy + dz * dz;
}

// ---------------- in-degree (layer-invariant) ----------------
__global__ __launch_bounds__(256) void k_cnt(const int* __restrict__ eidx,
                                             float* __restrict__ cnt) {
    int e = blockIdx.x * 256 + threadIdx.x;
    if (e >= N_EDGES) return;
    atomicAdd(&cnt[eidx[N_EDGES + e]], 1.0f);
}

// ---------------- counting sort of edges by i0 (T-row index) ----------------
__global__ __launch_bounds__(256) void k_hist(const float* __restrict__ d2g,
                                              int* __restrict__ hist) {
    int e = blockIdx.x * 256 + threadIdx.x;
    if (e >= N_EDGES) return;
    int i0 = (int)(d2g[e] * 128.0f);
    if (i0 > IMAX) i0 = IMAX;
    atomicAdd(&hist[i0], 1);
}

__global__ __launch_bounds__(256) void k_scan(const int* __restrict__ hist,
                                              int* __restrict__ offs) {
    __shared__ int buf[256];
    __shared__ int carryS;
    int tid = threadIdx.x;
    if (tid == 0) carryS = 0;
    __syncthreads();
    for (int base = 0; base < TROWS; base += 256) {
        int v = (base + tid < TROWS) ? hist[base + tid] : 0;
        buf[tid] = v;
        __syncthreads();
        for (int off = 1; off < 256; off <<= 1) {
            int t = (tid >= off) ? buf[tid - off] : 0;
            __syncthreads();
            buf[tid] += t;
            __syncthreads();
        }
        if (base + tid < TROWS) offs[base + tid] = carryS + buf[tid] - v;  // exclusive
        __syncthreads();
        if (tid == 0) carryS += buf[255];
        __syncthreads();
    }
}

__global__ __launch_bounds__(256) void k_copyi(const int* __restrict__ a,
                                               int* __restrict__ b) {
    int i = blockIdx.x * 256 + threadIdx.x;
    if (i < TROWS) b[i] = a[i];
}

__global__ __launch_bounds__(256) void k_scatter(const int* __restrict__ eidx,
                                                 const float* __restrict__ d2g,
                                                 int* __restrict__ cursor,
                                                 int* __restrict__ ssiP,
                                                 int* __restrict__ dsiP,
                                                 int* __restrict__ i0P,
                                                 float* __restrict__ frP) {
    int e = blockIdx.x * 256 + threadIdx.x;
    if (e >= N_EDGES) return;
    float t = d2g[e] * 128.0f;
    int i0 = (int)t;
    if (i0 > IMAX) i0 = IMAX;
    float fr = t - (float)i0;
    int pos = atomicAdd(&cursor[i0], 1);
    ssiP[pos] = eidx[e];
    dsiP[pos] = eidx[N_EDGES + e];
    i0P[pos] = i0;
    frP[pos] = fr;
}

// ---------------- fourier features on the d2 GRID (once) ----------------
__global__ __launch_bounds__(256) void k_feg(float* __restrict__ feG) {  // [TROWS][68]
    int g = blockIdx.x * 256 + threadIdx.x;
    if (g >= TROWS) return;
    float d2v = (float)g * 0.0078125f;   // g / 128, exact
    float* o = feG + (size_t)g * 68;
    float sc = 1.0f;
    #pragma unroll
    for (int i = 0; i < 32; ++i) {
        float x = d2v * sc;
        o[i] = sinf(x);
        o[32 + i] = cosf(x);
        sc *= 0.5f;
    }
    o[64] = d2v;
}

// ---------------- per-layer q-table: T[g][j] = fe(g/128) @ W1c + b1 ----------------
__global__ __launch_bounds__(256) void k_tab(const float* __restrict__ feG,   // [TROWS][68]
                                             const float* __restrict__ W1cp,  // [65][768]
                                             const float* __restrict__ b1p,   // [768]
                                             float* __restrict__ T) {         // [TROWS][648]
    __shared__ float feGs[32 * 68];
    __shared__ float W1s[65 * 36];
    const int tid = threadIdx.x;
    const int g0 = blockIdx.x * 32;
    for (int idx = tid; idx < 32 * 17; idx += 256) {
        int r = idx / 17, c = idx - r * 17;
        int gi = g0 + r;
        float4 v = make_float4(0, 0, 0, 0);
        if (gi < TROWS) v = *(const float4*)(feG + (size_t)gi * 68 + 4 * c);
        *(float4*)&feGs[r * 68 + 4 * c] = v;
    }
    const int gt = tid >> 3, ct = tid & 7;
    for (int jc = 0; jc < TCOLS; jc += 32) {
        __syncthreads();
        for (int idx = tid; idx < 65 * 32; idx += 256) {
            int k = idx >> 5, j = idx & 31;
            W1s[k * 36 + j] = W1cp[(size_t)k * 768 + jc + j];
        }
        __syncthreads();
        int gj = jc + 4 * ct;
        float4 q = *(const float4*)(b1p + gj);
        #pragma unroll 5
        for (int k = 0; k < 65; ++k) {
            float f = feGs[gt * 68 + k];
            float4 w = *(const float4*)&W1s[k * 36 + 4 * ct];
            q = f4fma(f, w, q);
        }
        int g = g0 + gt;
        if (g < TROWS && gj < TCOLS)
            *(float4*)(T + (size_t)g * TCOLS + gj) = q;
    }
}

// ---------------- W1ab prestage, all 5 layers: [5][128][1296] = [W1a|0|W1b|0] packed ----------------
__global__ __launch_bounds__(256) void k_w1ab5(const float* __restrict__ eW1,
                                               float* __restrict__ W1ab5) {
    int k = blockIdx.y;
    const float* W1 = eW1 + (size_t)k * 321 * 642;
    float* W1ab = W1ab5 + (size_t)k * 128 * 1296;
    int idx = blockIdx.x * 256 + threadIdx.x;
    if (idx >= 128 * 1296) return;
    int r = idx / 1296;
    int j = idx - r * 1296;
    float v = 0.f;
    if (j < 642) v = W1[(size_t)r * 642 + j];
    else if (j >= 648 && j < 1290) v = W1[(size_t)(128 + r) * 642 + (j - 648)];
    W1ab[idx] = v;
}

// ---------------- padded edge-weight prestage (all 5 layers) ----------------
__global__ __launch_bounds__(256) void k_wpre5(const float* __restrict__ eW1,
                                               const float* __restrict__ eb1,
                                               const float* __restrict__ eW2,
                                               float* __restrict__ W1cp5,   // [5][65][768]
                                               float* __restrict__ b1p5,    // [5][768]
                                               float* __restrict__ W2p5) {  // [5][768][32]
    int k = blockIdx.y;
    const float* W1 = eW1 + (size_t)k * 321 * 642;
    const float* b1 = eb1 + (size_t)k * 642;
    const float* W2 = eW2 + (size_t)k * 642 * 32;
    float* W1cp = W1cp5 + (size_t)k * 65 * 768;
    float* b1p  = b1p5 + (size_t)k * 768;
    float* W2p  = W2p5 + (size_t)k * 768 * 32;
    int idx = blockIdx.x * 256 + threadIdx.x;
    if (idx < 65 * 768) {
        int r = idx / 768, j = idx - r * 768;
        W1cp[idx] = (j < 642) ? W1[(size_t)(256 + r) * 642 + j] : 0.f;
    } else if (idx < 65 * 768 + 768) {
        int j = idx - 65 * 768;
        b1p[j] = (j < 642) ? b1[j] : 0.f;
    } else if (idx < 65 * 768 + 768 + 768 * 32) {
        int t = idx - (65 * 768 + 768);
        int j = t >> 5, c = t & 31;
        W2p[t] = (j < 642) ? W2[(size_t)j * 32 + c] : 0.f;
    }
}

// ---------------- fp32 GEMM 128x128 tile: C = act(actA(A) @ B + bias) ----------------
__global__ __launch_bounds__(256) void k_gemm(const float* __restrict__ A, int lda,
                                              const float* __restrict__ B, int ldb,
                                              const float* __restrict__ bias,
                                              float* __restrict__ C, int ldc,
                                              int M, int N, int K, int siluA, int siluOut) {
    __shared__ float As[32 * 132];
    __shared__ float Bs[32 * 132];
    const int tid = threadIdx.x;
    const int m0 = blockIdx.x * 128, n0 = blockIdx.y * 128;
    const int tm = tid >> 4, tn = tid & 15;

    float4 acc[8][2];
    #pragma unroll
    for (int r = 0; r < 8; ++r) { acc[r][0] = make_float4(0,0,0,0); acc[r][1] = make_float4(0,0,0,0); }

    float4 ra[4], rb[4];

#define GLOAD(kc_) do { \
    _Pragma("unroll") \
    for (int i_ = 0; i_ < 4; ++i_) { \
        int idx_ = tid + i_ * 256; \
        int m_ = idx_ >> 3, kq_ = idx_ & 7; \
        int gm_ = m0 + m_; \
        int cm_ = (gm_ < M) ? gm_ : (M - 1); \
        float4 a_ = *(const float4*)(A + (size_t)cm_ * lda + (kc_) + 4 * kq_); \
        if (gm_ >= M) a_ = make_float4(0,0,0,0); \
        ra[i_] = a_; \
    } \
    _Pragma("unroll") \
    for (int i_ = 0; i_ < 4; ++i_) { \
        int idx_ = tid + i_ * 256; \
        int r_ = idx_ >> 5, cq_ = idx_ & 31; \
        int gn_ = n0 + 4 * cq_; \
        float4 b_ = make_float4(0,0,0,0); \
        if (gn_ < N) b_ = *(const float4*)(B + (size_t)((kc_) + r_) * ldb + gn_); \
        rb[i_] = b_; \
    } \
} while (0)

    GLOAD(0);

    for (int kc = 0; kc < K; kc += 32) {
        #pragma unroll
        for (int i = 0; i < 4; ++i) {
            int idx = tid + i * 256;
            int m = idx >> 3, kq = idx & 7;
            float4 a = ra[i];
            if (siluA) { a.x = silu(a.x); a.y = silu(a.y); a.z = silu(a.z); a.w = silu(a.w); }
            As[(4 * kq + 0) * 132 + m] = a.x;
            As[(4 * kq + 1) * 132 + m] = a.y;
            As[(4 * kq + 2) * 132 + m] = a.z;
            As[(4 * kq + 3) * 132 + m] = a.w;
        }
        #pragma unroll
        for (int i = 0; i < 4; ++i) {
            int idx = tid + i * 256;
            int r = idx >> 5, cq = idx & 31;
            *(float4*)&Bs[r * 132 + 4 * cq] = rb[i];
        }
        __syncthreads();
        if (kc + 32 < K) GLOAD(kc + 32);   // in flight during FMA below
        #pragma unroll 4
        for (int kk = 0; kk < 32; ++kk) {
            float4 a0 = *(const float4*)&As[kk * 132 + 8 * tm];
            float4 a1 = *(const float4*)&As[kk * 132 + 8 * tm + 4];
            float4 b0 = *(const float4*)&Bs[kk * 132 + 4 * tn];
            float4 b1 = *(const float4*)&Bs[kk * 132 + 64 + 4 * tn];
            acc[0][0] = f4fma(a0.x, b0, acc[0][0]); acc[0][1] = f4fma(a0.x, b1, acc[0][1]);
            acc[1][0] = f4fma(a0.y, b0, acc[1][0]); acc[1][1] = f4fma(a0.y, b1, acc[1][1]);
            acc[2][0] = f4fma(a0.z, b0, acc[2][0]); acc[2][1] = f4fma(a0.z, b1, acc[2][1]);
            acc[3][0] = f4fma(a0.w, b0, acc[3][0]); acc[3][1] = f4fma(a0.w, b1, acc[3][1]);
            acc[4][0] = f4fma(a1.x, b0, acc[4][0]); acc[4][1] = f4fma(a1.x, b1, acc[4][1]);
            acc[5][0] = f4fma(a1.y, b0, acc[5][0]); acc[5][1] = f4fma(a1.y, b1, acc[5][1]);
            acc[6][0] = f4fma(a1.z, b0, acc[6][0]); acc[6][1] = f4fma(a1.z, b1, acc[6][1]);
            acc[7][0] = f4fma(a1.w, b0, acc[7][0]); acc[7][1] = f4fma(a1.w, b1, acc[7][1]);
        }
        __syncthreads();
    }
#undef GLOAD

    const int gnl = n0 + 4 * tn, gnh = n0 + 64 + 4 * tn;
    #pragma unroll
    for (int r = 0; r < 8; ++r) {
        int gm = m0 + 8 * tm + r;
        if (gm >= M) continue;
        float4 v0 = acc[r][0], v1 = acc[r][1];
        if (gnl < N) {
            if (bias) { v0.x += bias[gnl+0]; v0.y += bias[gnl+1]; v0.z += bias[gnl+2]; v0.w += bias[gnl+3]; }
            if (siluOut) { v0.x = silu(v0.x); v0.y = silu(v0.y); v0.z = silu(v0.z); v0.w = silu(v0.w); }
            *(float4*)&C[(size_t)gm * ldc + gnl] = v0;
        }
        if (gnh < N) {
            if (bias) { v1.x += bias[gnh+0]; v1.y += bias[gnh+1]; v1.z += bias[gnh+2]; v1.w += bias[gnh+3]; }
            if (siluOut) { v1.x = silu(v1.x); v1.y = silu(v1.y); v1.z = silu(v1.z); v1.w = silu(v1.w); }
            *(float4*)&C[(size_t)gm * ldc + gnh] = v1;
        }
    }
}

// ---------------- fp32 GEMM 64x128 tile: for small-N dispatches (grid fill) ----------------
// H2 GEMM was 79 blocks on 256 CUs (31% fill); H1/F* 158 (62%). BM=64 doubles the grid.
// Same k-pipeline, same ascending-k accumulation order -> outputs bit-identical to k_gemm.
__global__ __launch_bounds__(256) void k_gemm64(const float* __restrict__ A, int lda,
                                                const float* __restrict__ B, int ldb,
                                                const float* __restrict__ bias,
                                                float* __restrict__ C, int ldc,
                                                int M, int N, int K, int siluA, int siluOut) {
    __shared__ float As[32 * 68];
    __shared__ float Bs[32 * 132];
    const int tid = threadIdx.x;
    const int m0 = blockIdx.x * 64, n0 = blockIdx.y * 128;
    const int tm = tid >> 4, tn = tid & 15;   // tm 0..15 (4 rows each), tn 0..15 (8 cols)

    float4 acc[4][2];
    #pragma unroll
    for (int r = 0; r < 4; ++r) { acc[r][0] = make_float4(0,0,0,0); acc[r][1] = make_float4(0,0,0,0); }

    float4 ra[2], rb[4];

#define GLOAD64(kc_) do { \
    _Pragma("unroll") \
    for (int i_ = 0; i_ < 2; ++i_) { \
        int idx_ = tid + i_ * 256; \
        int m_ = idx_ >> 3, kq_ = idx_ & 7; \
        int gm_ = m0 + m_; \
        int cm_ = (gm_ < M) ? gm_ : (M - 1); \
        float4 a_ = *(const float4*)(A + (size_t)cm_ * lda + (kc_) + 4 * kq_); \
        if (gm_ >= M) a_ = make_float4(0,0,0,0); \
        ra[i_] = a_; \
    } \
    _Pragma("unroll") \
    for (int i_ = 0; i_ < 4; ++i_) { \
        int idx_ = tid + i_ * 256; \
        int r_ = idx_ >> 5, cq_ = idx_ & 31; \
        int gn_ = n0 + 4 * cq_; \
        float4 b_ = make_float4(0,0,0,0); \
        if (gn_ < N) b_ = *(const float4*)(B + (size_t)((kc_) + r_) * ldb + gn_); \
        rb[i_] = b_; \
    } \
} while (0)

    GLOAD64(0);

    for (int kc = 0; kc < K; kc += 32) {
        #pragma unroll
        for (int i = 0; i < 2; ++i) {
            int idx = tid + i * 256;
            int m = idx >> 3, kq = idx & 7;
            float4 a = ra[i];
            if (siluA) { a.x = silu(a.x); a.y = silu(a.y); a.z = silu(a.z); a.w = silu(a.w); }
            As[(4 * kq + 0) * 68 + m] = a.x;
            As[(4 * kq + 1) * 68 + m] = a.y;
            As[(4 * kq + 2) * 68 + m] = a.z;
            As[(4 * kq + 3) * 68 + m] = a.w;
        }
        #pragma unroll
        for (int i = 0; i < 4; ++i) {
            int idx = tid + i * 256;
            int r = idx >> 5, cq = idx & 31;
            *(float4*)&Bs[r * 132 + 4 * cq] = rb[i];
        }
        __syncthreads();
        if (kc + 32 < K) GLOAD64(kc + 32);   // in flight during FMA below
        #pragma unroll 4
        for (int kk = 0; kk < 32; ++kk) {
            float4 av = *(const float4*)&As[kk * 68 + 4 * tm];
            float4 b0 = *(const float4*)&Bs[kk * 132 + 4 * tn];
            float4 b1 = *(const float4*)&Bs[kk * 132 + 64 + 4 * tn];
            acc[0][0] = f4fma(av.x, b0, acc[0][0]); acc[0][1] = f4fma(av.x, b1, acc[0][1]);
            acc[1][0] = f4fma(av.y, b0, acc[1][0]); acc[1][1] = f4fma(av.y, b1, acc[1][1]);
            acc[2][0] = f4fma(av.z, b0, acc[2][0]); acc[2][1] = f4fma(av.z, b1, acc[2][1]);
            acc[3][0] = f4fma(av.w, b0, acc[3][0]); acc[3][1] = f4fma(av.w, b1, acc[3][1]);
        }
        __syncthreads();
    }
#undef GLOAD64

    const int gnl = n0 + 4 * tn, gnh = n0 + 64 + 4 * tn;
    #pragma unroll
    for (int r = 0; r < 4; ++r) {
        int gm = m0 + 4 * tm + r;
        if (gm >= M) continue;
        float4 v0 = acc[r][0], v1 = acc[r][1];
        if (gnl < N) {
            if (bias) { v0.x += bias[gnl+0]; v0.y += bias[gnl+1]; v0.z += bias[gnl+2]; v0.w += bias[gnl+3]; }
            if (siluOut) { v0.x = silu(v0.x); v0.y = silu(v0.y); v0.z = silu(v0.z); v0.w = silu(v0.w); }
            *(float4*)&C[(size_t)gm * ldc + gnl] = v0;
        }
        if (gnh < N) {
            if (bias) { v1.x += bias[gnh+0]; v1.y += bias[gnh+1]; v1.z += bias[gnh+2]; v1.w += bias[gnh+3]; }
            if (siluOut) { v1.x = silu(v1.x); v1.y = silu(v1.y); v1.z = silu(v1.z); v1.w = silu(v1.w); }
            *(float4*)&C[(size_t)gm * ldc + gnh] = v1;
        }
    }
}

// ---------------- fused edge kernel v7: v3 bounds (VGPR-84 prefetch) + v6 LDS (5-block) ----------------
// Cross-round evidence: (256,3) -> VGPR 84, partial prefetch honored, dur 278 (v3, best);
// (256,4) -> VGPR 64, prefetch sunk to use, dur 285 (v6) despite +8pp occupancy.
// v7 combines the winning bounds with the single-W2s 28.7KB LDS (5-block ceiling):
// partial prefetch AND occupancy headroom. Bit-identical math, same barrier structure.
__global__ __launch_bounds__(256, 3) void k_edge(const int* __restrict__ ssiP,
                                                 const int* __restrict__ dsiP,
                                                 const int* __restrict__ i0P,
                                                 const float* __restrict__ frP,
                                                 const float* __restrict__ T,     // [TROWS][648]
                                                 const float* __restrict__ Pab,   // [N_NODES][1296]
                                                 const float* __restrict__ W2p,   // [768][32]
                                                 const float* __restrict__ b2,
                                                 const float* __restrict__ eng,
                                                 const float* __restrict__ enb,
                                                 float* __restrict__ S) {
    __shared__ float Zs[64 * 70];        // 17920 B; overlaid by m2s[64][36] in epilogue
    __shared__ float W2s[64 * 36];       // single-buffered W2 chunk, 9216 B
    __shared__ int dsi[EPB], ssi[EPB], i0s[EPB];
    __shared__ float frs[EPB];
    __shared__ float cpar[96];

    const int tid = threadIdx.x;
    // XCD-chunked bijective swizzle (nwg=2500, 8 XCDs: q=312, r=4 -> first 4 XCDs 313 blocks)
    const int bid = blockIdx.x;
    const int xcd = bid & 7, bpos = bid >> 3;
    const int wg = (xcd < 4) ? xcd * 313 + bpos : 1252 + (xcd - 4) * 312 + bpos;
    const int eb = wg * EPB;
    const int lane = tid & 31;           // edge-pair index (both phases)
    const int grp = tid >> 5;            // col group: phase-1 8 cols, phase-2 4 out-cols

    if (tid < EPB) {
        ssi[tid] = ssiP[eb + tid];
        dsi[tid] = dsiP[eb + tid];
        i0s[tid] = i0P[eb + tid];
        frs[tid] = frP[eb + tid];
    }
    if (tid < 32) cpar[tid] = b2[tid];
    else if (tid < 64) cpar[tid] = eng[tid - 32];
    else if (tid < 96) cpar[tid] = enb[tid - 64];
    __syncthreads();

    int dsr[2], ssr[2], i0r[2];
    float frr[2];
    #pragma unroll
    for (int i = 0; i < 2; ++i) {
        int e = 2 * lane + i;
        dsr[i] = dsi[e]; ssr[i] = ssi[e];
        i0r[i] = i0s[e]; frr[i] = frs[e];
    }

    float4 accm[2];
    accm[0] = make_float4(0,0,0,0);
    accm[1] = make_float4(0,0,0,0);

    // prefetch registers (next chunk's T rows, Pab rows, W2 chunk)
    float4 rA0[2], rA1[2], rB0[2], rB1[2];
    float4 rP0[2], rP1[2], rQ0[2], rQ1[2];
    float4 rw0, rw1;

#define PREFETCH(cn) do { \
    const int colb_ = 64 * (cn) + 8 * grp; \
    if (colb_ < TCOLS) { \
        _Pragma("unroll") \
        for (int i_ = 0; i_ < 2; ++i_) { \
            const float* t0_ = T + (size_t)i0r[i_] * TCOLS + colb_; \
            rA0[i_] = *(const float4*)t0_; \
            rA1[i_] = *(const float4*)(t0_ + 4); \
            rB0[i_] = *(const float4*)(t0_ + TCOLS); \
            rB1[i_] = *(const float4*)(t0_ + TCOLS + 4); \
            const float* pr_ = Pab + (size_t)dsr[i_] * PSTRIDE + colb_; \
            const float* qr_ = Pab + (size_t)ssr[i_] * PSTRIDE + JP + colb_; \
            rP0[i_] = *(const float4*)pr_; rP1[i_] = *(const float4*)(pr_ + 4); \
            rQ0[i_] = *(const float4*)qr_; rQ1[i_] = *(const float4*)(qr_ + 4); \
        } \
    } \
    const float* ws_ = W2p + (size_t)(64 * (cn)) * 32 + 8 * tid; \
    rw0 = *(const float4*)ws_; rw1 = *(const float4*)(ws_ + 4); \
} while (0)

    PREFETCH(0);

    for (int ch = 0; ch < 11; ++ch) {
        const int colb = 64 * ch + 8 * grp;

        // ---- compute qa from prefetched regs (vmcnt wait lands here, post-FMA) ----
        float qa[2][8];
        if (colb < TCOLS) {
            #pragma unroll
            for (int i = 0; i < 2; ++i) {
                float f = frr[i];
                qa[i][0] = silu(fmaf(f, rB0[i].x - rA0[i].x, rA0[i].x) + rP0[i].x + rQ0[i].x);
                qa[i][1] = silu(fmaf(f, rB0[i].y - rA0[i].y, rA0[i].y) + rP0[i].y + rQ0[i].y);
                qa[i][2] = silu(fmaf(f, rB0[i].z - rA0[i].z, rA0[i].z) + rP0[i].z + rQ0[i].z);
                qa[i][3] = silu(fmaf(f, rB0[i].w - rA0[i].w, rA0[i].w) + rP0[i].w + rQ0[i].w);
                qa[i][4] = silu(fmaf(f, rB1[i].x - rA1[i].x, rA1[i].x) + rP1[i].x + rQ1[i].x);
                qa[i][5] = silu(fmaf(f, rB1[i].y - rA1[i].y, rA1[i].y) + rP1[i].y + rQ1[i].y);
                qa[i][6] = silu(fmaf(f, rB1[i].z - rA1[i].z, rA1[i].z) + rP1[i].z + rQ1[i].z);
                qa[i][7] = silu(fmaf(f, rB1[i].w - rA1[i].w, rA1[i].w) + rP1[i].w + rQ1[i].w);
            }
        } else {
            #pragma unroll
            for (int i = 0; i < 2; ++i)
                #pragma unroll
                for (int c = 0; c < 8; ++c) qa[i][c] = 0.f;
        }

        __syncthreads();   // bA: previous FMA done -> Zs + W2s free for overwrite

        // Zs write: rows j = 8*grp..8*grp+7, col pair 2*lane
        #pragma unroll
        for (int jj = 0; jj < 8; ++jj) {
            float2 z2;
            z2.x = qa[0][jj]; z2.y = qa[1][jj];
            *(float2*)&Zs[(8 * grp + jj) * 70 + 2 * lane] = z2;
        }
        // W2s write from prefetched regs (rows 64ch..64ch+63 of W2p)
        {
            int wrow = tid >> 2;
            int wc0 = (2 * tid) & 7;
            *(float4*)&W2s[wrow * 36 + 4 * wc0] = rw0;
            *(float4*)&W2s[wrow * 36 + 4 * (wc0 + 1)] = rw1;
        }

        __syncthreads();   // bB: Zs + W2s published

        if (ch < 10) PREFETCH(ch + 1);   // issued BEFORE FMA -> in flight during it

        #pragma unroll 8
        for (int kk = 0; kk < 64; ++kk) {
            float2 z2 = *(const float2*)&Zs[kk * 70 + 2 * lane];
            float4 w4 = *(const float4*)&W2s[kk * 36 + 4 * grp];
            accm[0] = f4fma(z2.x, w4, accm[0]);
            accm[1] = f4fma(z2.y, w4, accm[1]);
        }
    }
#undef PREFETCH

    // ---- epilogue: m2 = silu(accm + b2), LN, scatter ----
    __syncthreads();                 // FMA(10) done -> Zs reusable as m2s
    float* m2s = Zs;
    {
        float4 bb2 = *(const float4*)&cpar[4 * grp];
        #pragma unroll
        for (int i = 0; i < 2; ++i) {
            int e = 2 * lane + i;
            float4 o;
            o.x = silu(accm[i].x + bb2.x);
            o.y = silu(accm[i].y + bb2.y);
            o.z = silu(accm[i].z + bb2.z);
            o.w = silu(accm[i].w + bb2.w);
            *(float4*)&m2s[e * 36 + 4 * grp] = o;
        }
    }
    __syncthreads();
    {
        // 4 threads per edge: thread (e = tid>>2, q = tid&3) handles cols 8q..8q+7
        int e = tid >> 2, q = tid & 3;
        float4 v0 = *(const float4*)&m2s[e * 36 + 8 * q];
        float4 v1 = *(const float4*)&m2s[e * 36 + 8 * q + 4];
        float s  = v0.x + v0.y + v0.z + v0.w + v1.x + v1.y + v1.z + v1.w;
        float ss = v0.x*v0.x + v0.y*v0.y + v0.z*v0.z + v0.w*v0.w
                 + v1.x*v1.x + v1.y*v1.y + v1.z*v1.z + v1.w*v1.w;
        s  += __shfl_xor(s, 1, 64);  ss += __shfl_xor(ss, 1, 64);
        s  += __shfl_xor(s, 2, 64);  ss += __shfl_xor(ss, 2, 64);
        float mean = s * 0.03125f;
        float var = ss * 0.03125f - mean * mean;
        float rstd = 1.0f / sqrtf(var + EPS);
        int d = dsi[e];
        float* Sp = S + (size_t)d * 32 + 8 * q;
        const float* gg = cpar + 32 + 8 * q;
        const float* bbv = cpar + 64 + 8 * q;
        float vv[8] = {v0.x, v0.y, v0.z, v0.w, v1.x, v1.y, v1.z, v1.w};
        #pragma unroll
        for (int c = 0; c < 8; ++c)
            atomicAdd(&Sp[c], (vv[c] - mean) * rstd * gg[c] + bbv[c]);
    }
}

// ---------------- node prep: H0 = [LN(feats) | LN(S/cnt)] ----------------
__global__ __launch_bounds__(128) void k_prep(const float* __restrict__ featsk,
                                              const float* __restrict__ S,
                                              const float* __restrict__ cnt,
                                              const float* __restrict__ nn1g,
                                              const float* __restrict__ nn1b,
                                              const float* __restrict__ eng,
                                              const float* __restrict__ enb,
                                              float* __restrict__ H0) {
    int n = blockIdx.x, tid = threadIdx.x;
    __shared__ float red[4];
    float x = featsk[(size_t)n * 768 + tid];
    float s = wave_sum64(x), ss = wave_sum64(x * x);
    if ((tid & 63) == 0) { red[(tid >> 6) * 2] = s; red[(tid >> 6) * 2 + 1] = ss; }
    __syncthreads();
    float S1 = red[0] + red[2], S2 = red[1] + red[3];
    float mean = S1 * (1.0f / 128.0f);
    float var = S2 * (1.0f / 128.0f) - mean * mean;
    float rstd = 1.0f / sqrtf(var + EPS);
    H0[(size_t)n * 160 + tid] = (x - mean) * rstd * nn1g[tid] + nn1b[tid];
    if (tid < 32) {
        float inv = 1.0f / fmaxf(cnt[n], 1.0f);
        float v = S[(size_t)n * 32 + tid] * inv;
        float s2 = v, q2 = v * v;
        #pragma unroll
        for (int off = 16; off > 0; off >>= 1) {
            s2 += __shfl_xor(s2, off, 64);
            q2 += __shfl_xor(q2, off, 64);
        }
        float m2 = s2 * (1.0f / 32.0f);
        float va = q2 * (1.0f / 32.0f) - m2 * m2;
        float rs = 1.0f / sqrtf(va + EPS);
        H0[(size_t)n * 160 + 128 + tid] = (v - m2) * rs * eng[tid] + enb[tid];
    }
}

// ---------------- LN + residual ----------------
__global__ __launch_bounds__(128) void k_ln_res(const float* __restrict__ H2,
                                                float* __restrict__ feats_all, int k,
                                                const float* __restrict__ g,
                                                const float* __restrict__ b) {
    int n = blockIdx.x, tid = threadIdx.x;
    __shared__ float red[4];
    float x = H2[(size_t)n * 128 + tid];
    float s = wave_sum64(x), ss = wave_sum64(x * x);
    if ((tid & 63) == 0) { red[(tid >> 6) * 2] = s; red[(tid >> 6) * 2 + 1] = ss; }
    __syncthreads();
    float S1 = red[0] + red[2], S2 = red[1] + red[3];
    float mean = S1 * (1.0f / 128.0f);
    float var = S2 * (1.0f / 128.0f) - mean * mean;
    float rstd = 1.0f / sqrtf(var + EPS);
    float v = (x - mean) * rstd * g[tid] + b[tid];
    float f = feats_all[(size_t)n * 768 + k * 128 + tid];
    feats_all[(size_t)n * 768 + (k + 1) * 128 + tid] = f + v;
}

// ---------------- graph pooling (batch sorted -> run-length accum) ----------------
__global__ __launch_bounds__(256) void k_pool(const float* __restrict__ F,
                                              const int* __restrict__ batch,
                                              float* __restrict__ G,
                                              float* __restrict__ cntg) {
    __shared__ int bL[32];
    int b0 = blockIdx.x * 32;
    int tid = threadIdx.x;
    int nmax = min(32, N_NODES - b0);
    if (nmax <= 0) return;
    if (tid < nmax) bL[tid] = batch[b0 + tid];
    __syncthreads();
    float accv = 0.f;
    int cur = -1;
    for (int i = 0; i < nmax; ++i) {
        int g = bL[i];
        if (g != cur) {
            if (cur >= 0) atomicAdd(&G[(size_t)cur * 256 + tid], accv);
            cur = g; accv = 0.f;
        }
        accv += F[(size_t)(b0 + i) * 256 + tid];
    }
    if (cur >= 0) atomicAdd(&G[(size_t)cur * 256 + tid], accv);
    if (tid == 0)
        for (int i = 0; i < nmax; ++i) atomicAdd(&cntg[bL[i]], 1.0f);
}

// ---------------- per-graph MLP head ----------------
__global__ __launch_bounds__(256) void k_graph(const float* __restrict__ G,
                                               const float* __restrict__ cntg,
                                               const float* __restrict__ g1W,
                                               const float* __restrict__ g1b,
                                               const float* __restrict__ g2W,
                                               const float* __restrict__ g2b,
                                               const float* __restrict__ g3W,
                                               const float* __restrict__ g3b,
                                               float* __restrict__ out) {
    __shared__ float X[256], Y[256], red[4];
    int g = blockIdx.x, tid = threadIdx.x;
    float inv = 1.0f / fmaxf(cntg[g], 1.0f);
    X[tid] = G[(size_t)g * 256 + tid] * inv;
    __syncthreads();
    float a = g1b[tid];
    for (int j = 0; j < 256; ++j) a = fmaf(X[j], g1W[(size_t)j * 256 + tid], a);
    Y[tid] = silu(a);
    __syncthreads();
    a = g2b[tid];
    for (int j = 0; j < 256; ++j) a = fmaf(Y[j], g2W[(size_t)j * 256 + tid], a);
    float z = silu(a);
    float p = z * g3W[tid];
    p = wave_sum64(p);
    if ((tid & 63) == 0) red[tid >> 6] = p;
    __syncthreads();
    if (tid == 0) out[g] = red[0] + red[1] + red[2] + red[3] + g3b[0];
}

extern "C" void kernel_launch(void* const* d_in, const int* in_sizes, int n_in,
                              void* d_out, int out_size, void* d_ws, size_t ws_size,
                              hipStream_t stream) {
    const int*   atomids = (const int*)d_in[0];
    const float* coords  = (const float*)d_in[1];
    const int*   eidx    = (const int*)d_in[2];
    const int*   batch   = (const int*)d_in[3];
    const float* emb_w   = (const float*)d_in[4];
    const float* eW1     = (const float*)d_in[5];
    const float* eb1     = (const float*)d_in[6];
    const float* eW2     = (const float*)d_in[7];
    const float* eb2     = (const float*)d_in[8];
    const float* en_g    = (const float*)d_in[9];
    const float* en_b    = (const float*)d_in[10];
    const float* nn1_g   = (const float*)d_in[11];
    const float* nn1_b   = (const float*)d_in[12];
    const float* nW1     = (const float*)d_in[13];
    const float* nb1     = (const float*)d_in[14];
    const float* nW2     = (const float*)d_in[15];
    const float* nb2     = (const float*)d_in[16];
    const float* nn2_g   = (const float*)d_in[17];
    const float* nn2_b   = (const float*)d_in[18];
    const float* f1W     = (const float*)d_in[19];
    const float* f1b     = (const float*)d_in[20];
    const float* f2W     = (const float*)d_in[21];
    const float* f2b     = (const float*)d_in[22];
    const float* f3W     = (const float*)d_in[23];
    const float* f3b     = (const float*)d_in[24];
    const float* g1W     = (const float*)d_in[25];
    const float* g1b     = (const float*)d_in[26];
    const float* g2W     = (const float*)d_in[27];
    const float* g2b     = (const float*)d_in[28];
    const float* g3W     = (const float*)d_in[29];
    const float* g3b     = (const float*)d_in[30];
    float* out = (float*)d_out;

    float* ws = (float*)d_ws;
    float* feats_all = ws;                        // [10000][768]
    float* d2g   = ws + 7680000;                  // [160000]
    float* Pab   = ws + 7840000;                  // [10000][1296]
    float* S     = ws + 20800000;                 // [10000][32]
    float* cnt   = ws + 21120000;                 // [10000]
    float* W1ab5 = ws + 21130000;                 // [5][128][1296]
    float* W1cp5 = ws + 21959440;                 // [5][65][768]
    float* b1p5  = ws + 22209040;                 // [5][768]
    float* W2p5  = ws + 22212880;                 // [5][768][32]
    float* feG   = ws + 22335760;                 // [12289][68]
    float* T     = ws + 23171412;                 // [12289][648]
    float* G     = ws + 31134684;                 // [64][256]
    float* cntg  = ws + 31151068;                 // [64]
    int*   histI = (int*)(ws + 31151132);         // [12304]
    int*   offs  = (int*)(ws + 31163436);         // [12304]
    int*   cursor= (int*)(ws + 31175740);         // [12304]
    int*   ssiP  = (int*)(ws + 31188044);         // [160000]
    int*   dsiP  = (int*)(ws + 31348044);         // [160000]
    int*   i0P   = (int*)(ws + 31508044);         // [160000]
    float* frP   = ws + 31668044;                 // [160000] (end ~31.83M floats = 127.3 MB)
    // node-phase temporaries overlay Pab (dead between phases; 12.96M floats available)
    float* H0 = Pab;                              // [10000][160]
    float* H1 = Pab + 1600000;                    // [10000][256]
    float* H2 = Pab + 4160000;                    // [10000][128]
    float* F1 = Pab;                              // [10000][256]
    float* F2 = Pab + 2560000;                    // [10000][256]
    float* F3 = Pab + 5120000;                    // [10000][256]

    k_embed<<<N_NODES, 128, 0, stream>>>(atomids, emb_w, feats_all);
    k_d2<<<(N_EDGES + 255) / 256, 256, 0, stream>>>(coords, eidx, d2g);
    hipMemsetAsync(cnt, 0, 10000 * sizeof(float), stream);
    k_cnt<<<(N_EDGES + 255) / 256, 256, 0, stream>>>(eidx, cnt);
    hipMemsetAsync(histI, 0, 12304 * sizeof(int), stream);
    k_hist<<<(N_EDGES + 255) / 256, 256, 0, stream>>>(d2g, histI);
    k_scan<<<1, 256, 0, stream>>>(histI, offs);
    k_copyi<<<(TROWS + 255) / 256, 256, 0, stream>>>(offs, cursor);
    k_scatter<<<(N_EDGES + 255) / 256, 256, 0, stream>>>(eidx, d2g, cursor,
                                                         ssiP, dsiP, i0P, frP);
    k_feg<<<(TROWS + 255) / 256, 256, 0, stream>>>(feG);
    k_w1ab5<<<dim3(648, 5), 256, 0, stream>>>(eW1, W1ab5);
    k_wpre5<<<dim3(294, 5), 256, 0, stream>>>(eW1, eb1, eW2, W1cp5, b1p5, W2p5);

    for (int k = 0; k < NK; ++k) {
        const float* eb2k = eb2 + (size_t)k * 32;
        const float* engk = en_g + (size_t)k * 32;
        const float* enbk = en_b + (size_t)k * 32;
        const float* nn1gk = nn1_g + (size_t)k * 128;
        const float* nn1bk = nn1_b + (size_t)k * 128;
        const float* nW1k = nW1 + (size_t)k * 160 * 256;
        const float* nb1k = nb1 + (size_t)k * 256;
        const float* nW2k = nW2 + (size_t)k * 256 * 128;
        const float* nb2k = nb2 + (size_t)k * 128;
        const float* nn2gk = nn2_g + (size_t)k * 128;
        const float* nn2bk = nn2_b + (size_t)k * 128;

        k_tab<<<(TROWS + 31) / 32, 256, 0, stream>>>(feG,
                                                     W1cp5 + (size_t)k * 65 * 768,
                                                     b1p5 + (size_t)k * 768, T);
        // MUST write all 1296 Pab columns (k_edge reads zero-padding up to col 1295)
        k_gemm<<<dim3(79, 11), 256, 0, stream>>>(feats_all + k * 128, 768,
                                                 W1ab5 + (size_t)k * 128 * 1296, 1296,
                                                 nullptr, Pab, 1296, N_NODES, 1296, 128, 0, 0);
        hipMemsetAsync(S, 0, (size_t)320000 * sizeof(float), stream);
        k_edge<<<N_EDGES / EPB, 256, 0, stream>>>(ssiP, dsiP, i0P, frP, T, Pab,
                                                  W2p5 + (size_t)k * 768 * 32,
                                                  eb2k, engk, enbk, S);
        k_prep<<<N_NODES, 128, 0, stream>>>(feats_all + k * 128, S, cnt,
                                            nn1gk, nn1bk, engk, enbk, H0);
        k_gemm64<<<dim3(157, 2), 256, 0, stream>>>(H0, 160, nW1k, 256, nb1k, H1, 256,
                                                   N_NODES, 256, 160, 0, 1);
        k_gemm64<<<dim3(157, 1), 256, 0, stream>>>(H1, 256, nW2k, 128, nb2k, H2, 128,
                                                   N_NODES, 128, 256, 0, 0);
        k_ln_res<<<N_NODES, 128, 0, stream>>>(H2, feats_all, k, nn2gk, nn2bk);
    }

    // final node MLP (F1/F2/F3 overlay Pab)
    k_gemm64<<<dim3(157, 2), 256, 0, stream>>>(feats_all, 768, f1W, 256, f1b, F1, 256,
                                               N_NODES, 256, 768, 1, 1);
    k_gemm64<<<dim3(157, 2), 256, 0, stream>>>(F1, 256, f2W, 256, f2b, F2, 256,
                                               N_NODES, 256, 256, 0, 1);
    k_gemm64<<<dim3(157, 2), 256, 0, stream>>>(F2, 256, f3W, 256, f3b, F3, 256,
                                               N_NODES, 256, 256, 0, 1);

    hipMemsetAsync(G, 0, (size_t)(16384 + 64) * sizeof(float), stream);
    k_pool<<<313, 256, 0, stream>>>(F3, batch, G, cntg);
    k_graph<<<N_GRAPHS, 256, 0, stream>>>(G, cntg, g1W, g1b, g2W, g2b, g3W, g3b, out);
}